// Round 5
// baseline (219.030 us; speedup 1.0000x reference)
//
#include <hip/hip_runtime.h>
#include <hip/hip_bf16.h>

// B=8, E=64, CIN=C=PRE=128. fp32 I/O; bf16 MFMA everywhere GEMM-shaped.

typedef unsigned short u16;
typedef unsigned int u32;
typedef short s16x8 __attribute__((ext_vector_type(8)));
typedef float f32x4 __attribute__((ext_vector_type(4)));

#define NB 8
#define NE 64
#define NC 128

__device__ __forceinline__ float b2f(u16 u) { return __uint_as_float(((u32)u) << 16); }
__device__ __forceinline__ u16 f2b(float f) {
    u32 x = __float_as_uint(f);
    u32 r = (x + 0x7fffu + ((x >> 16) & 1u)) >> 16;   // RNE
    return (u16)r;
}
__device__ __forceinline__ float lk(float v) { return v >= 0.f ? v : 0.1f * v; }
__device__ __forceinline__ s16x8 cvt8(const float* p) {
    float4 a = ((const float4*)p)[0], c = ((const float4*)p)[1];
    s16x8 r;
    r[0] = (short)f2b(a.x); r[1] = (short)f2b(a.y); r[2] = (short)f2b(a.z); r[3] = (short)f2b(a.w);
    r[4] = (short)f2b(c.x); r[5] = (short)f2b(c.y); r[6] = (short)f2b(c.z); r[7] = (short)f2b(c.w);
    return r;
}

// ---------------- K0: conv weights -> bf16 MFMA A-fragment order (validated R3/R4)
__global__ __launch_bounds__(256) void k_prepw(const float* __restrict__ w1, const float* __restrict__ w2,
                                               u16* __restrict__ wA1, u16* __restrict__ wA2) {
    int idx = blockIdx.x * 256 + threadIdx.x;
    if (idx < 49152) {
        int e = idx & 7, lane = (idx >> 3) & 63, mtg = (idx >> 9) & 7, kc = idx >> 12;
        int o = mtg * 16 + (lane & 15), c = kc * 32 + ((lane >> 4) << 3) + e;
        wA1[idx] = f2b(w1[o * 384 + c]);
    } else {
        int id2 = idx - 49152;
        if (id2 < 147456) {
            int e = id2 & 7, lane = (id2 >> 3) & 63, mtg = (id2 >> 9) & 7;
            int kc = (id2 >> 12) & 3, tap = id2 >> 14;
            int o = mtg * 16 + (lane & 15), c = kc * 32 + ((lane >> 4) << 3) + e;
            wA2[id2] = f2b(w2[(o * 128 + c) * 9 + tap]);
        }
    }
}

// ---------------- K1: fused front-end. One block per b (8 blocks, 4 waves).
// GEMMs: xf=xc1*x, yf=yc1*y, linx=xlw*x, liny=ylw*y; plus xs/yo, Lw, gb.
__global__ __launch_bounds__(256) void k_front(const float* __restrict__ x, const float* __restrict__ y,
                                               const float* __restrict__ xc1, const float* __restrict__ yc1,
                                               const float* __restrict__ xc2w, const float* __restrict__ xc2b,
                                               const float* __restrict__ yc2w, const float* __restrict__ yc2b,
                                               const float* __restrict__ xlw, const float* __restrict__ ylw,
                                               const float* __restrict__ etab, const float* __restrict__ econv,
                                               const int* __restrict__ edge_mat, const float* __restrict__ m_bias,
                                               u16* __restrict__ xfb, u16* __restrict__ yfb,
                                               float* __restrict__ xfT, float* __restrict__ yfT,
                                               u16* __restrict__ xlT, u16* __restrict__ ylT,
                                               float* __restrict__ Lw, float* __restrict__ gb) {
    int b = blockIdx.x;
    int t = threadIdx.x;
    int lane = t & 63, w = t >> 6, l15 = lane & 15, q4 = lane >> 4;
    __shared__ u16 sxT[64][136];   // [m][i] = x[b][i][m] bf16
    __shared__ u16 syT[64][136];
    __shared__ float sXs[64], sYo[64], sEd[16];

    if (t < 10) {
        float s = 0.f;
        for (int d = 0; d < 32; ++d) s += etab[t * 32 + d] * econv[d];
        sEd[t] = lk(s);
    }
    // stage transposed bf16
    {
        int i = t >> 1, m0 = (t & 1) * 32;
        const float4* px = (const float4*)(x + (b * 128 + i) * 64 + m0);
        const float4* py = (const float4*)(y + (b * 128 + i) * 64 + m0);
#pragma unroll
        for (int q = 0; q < 8; ++q) {
            float4 v = px[q];
            int m = m0 + q * 4;
            sxT[m + 0][i] = f2b(v.x); sxT[m + 1][i] = f2b(v.y);
            sxT[m + 2][i] = f2b(v.z); sxT[m + 3][i] = f2b(v.w);
            float4 u = py[q];
            syT[m + 0][i] = f2b(u.x); syT[m + 1][i] = f2b(u.y);
            syT[m + 2][i] = f2b(u.z); syT[m + 3][i] = f2b(u.w);
        }
    }
    __syncthreads();

    int m = w * 16 + l15;   // this wave's N-column (entity index)

    // GEMM xf: xf[c][m] = sum_i xc1[c][i] x[i][m]
    {
        f32x4 acc[8];
#pragma unroll
        for (int mt = 0; mt < 8; ++mt) acc[mt] = (f32x4)(0.f);
#pragma unroll
        for (int kt = 0; kt < 4; ++kt) {
            s16x8 bfr = *(const s16x8*)&sxT[m][kt * 32 + q4 * 8];
#pragma unroll
            for (int mt = 0; mt < 8; ++mt) {
                s16x8 af = cvt8(xc1 + (mt * 16 + l15) * 128 + kt * 32 + q4 * 8);
                acc[mt] = __builtin_amdgcn_mfma_f32_16x16x32_bf16(af, bfr, acc[mt], 0, 0, 0);
            }
        }
        float xsp = 0.f;
#pragma unroll
        for (int mt = 0; mt < 8; ++mt) {
            int c0 = mt * 16 + q4 * 4;
            f32x4 a = acc[mt];
            xfb[(b * 128 + c0 + 0) * 64 + m] = f2b(a[0]);
            xfb[(b * 128 + c0 + 1) * 64 + m] = f2b(a[1]);
            xfb[(b * 128 + c0 + 2) * 64 + m] = f2b(a[2]);
            xfb[(b * 128 + c0 + 3) * 64 + m] = f2b(a[3]);
            *(float4*)(xfT + (b * 64 + m) * 128 + c0) = make_float4(a[0], a[1], a[2], a[3]);
            float4 wv = *(const float4*)(xc2w + c0);
            xsp += wv.x * a[0] + wv.y * a[1] + wv.z * a[2] + wv.w * a[3];
        }
        xsp += __shfl_xor(xsp, 16);
        xsp += __shfl_xor(xsp, 32);
        if (q4 == 0) sXs[m] = xsp + xc2b[0];
    }
    // GEMM yf
    {
        f32x4 acc[8];
#pragma unroll
        for (int mt = 0; mt < 8; ++mt) acc[mt] = (f32x4)(0.f);
#pragma unroll
        for (int kt = 0; kt < 4; ++kt) {
            s16x8 bfr = *(const s16x8*)&syT[m][kt * 32 + q4 * 8];
#pragma unroll
            for (int mt = 0; mt < 8; ++mt) {
                s16x8 af = cvt8(yc1 + (mt * 16 + l15) * 128 + kt * 32 + q4 * 8);
                acc[mt] = __builtin_amdgcn_mfma_f32_16x16x32_bf16(af, bfr, acc[mt], 0, 0, 0);
            }
        }
        float ysp = 0.f;
#pragma unroll
        for (int mt = 0; mt < 8; ++mt) {
            int c0 = mt * 16 + q4 * 4;
            f32x4 a = acc[mt];
            yfb[(b * 128 + c0 + 0) * 64 + m] = f2b(a[0]);
            yfb[(b * 128 + c0 + 1) * 64 + m] = f2b(a[1]);
            yfb[(b * 128 + c0 + 2) * 64 + m] = f2b(a[2]);
            yfb[(b * 128 + c0 + 3) * 64 + m] = f2b(a[3]);
            *(float4*)(yfT + (b * 64 + m) * 128 + c0) = make_float4(a[0], a[1], a[2], a[3]);
            float4 wv = *(const float4*)(yc2w + c0);
            ysp += wv.x * a[0] + wv.y * a[1] + wv.z * a[2] + wv.w * a[3];
        }
        ysp += __shfl_xor(ysp, 16);
        ysp += __shfl_xor(ysp, 32);
        if (q4 == 0) sYo[m] = ysp + yc2b[0];
    }
    // GEMM linx: x_lin[i][n] -> xlT[b][i][n] bf16
    {
        f32x4 acc[8];
#pragma unroll
        for (int mt = 0; mt < 8; ++mt) acc[mt] = (f32x4)(0.f);
#pragma unroll
        for (int kt = 0; kt < 4; ++kt) {
            s16x8 bfr = *(const s16x8*)&sxT[m][kt * 32 + q4 * 8];
#pragma unroll
            for (int mt = 0; mt < 8; ++mt) {
                s16x8 af = cvt8(xlw + (mt * 16 + l15) * 128 + kt * 32 + q4 * 8);
                acc[mt] = __builtin_amdgcn_mfma_f32_16x16x32_bf16(af, bfr, acc[mt], 0, 0, 0);
            }
        }
#pragma unroll
        for (int mt = 0; mt < 8; ++mt) {
            int i0 = mt * 16 + q4 * 4;
            f32x4 a = acc[mt];
            xlT[(b * 128 + i0 + 0) * 64 + m] = f2b(a[0]);
            xlT[(b * 128 + i0 + 1) * 64 + m] = f2b(a[1]);
            xlT[(b * 128 + i0 + 2) * 64 + m] = f2b(a[2]);
            xlT[(b * 128 + i0 + 3) * 64 + m] = f2b(a[3]);
        }
    }
    // GEMM liny -> ylT
    {
        f32x4 acc[8];
#pragma unroll
        for (int mt = 0; mt < 8; ++mt) acc[mt] = (f32x4)(0.f);
#pragma unroll
        for (int kt = 0; kt < 4; ++kt) {
            s16x8 bfr = *(const s16x8*)&syT[m][kt * 32 + q4 * 8];
#pragma unroll
            for (int mt = 0; mt < 8; ++mt) {
                s16x8 af = cvt8(ylw + (mt * 16 + l15) * 128 + kt * 32 + q4 * 8);
                acc[mt] = __builtin_amdgcn_mfma_f32_16x16x32_bf16(af, bfr, acc[mt], 0, 0, 0);
            }
        }
#pragma unroll
        for (int mt = 0; mt < 8; ++mt) {
            int i0 = mt * 16 + q4 * 4;
            f32x4 a = acc[mt];
            ylT[(b * 128 + i0 + 0) * 64 + m] = f2b(a[0]);
            ylT[(b * 128 + i0 + 1) * 64 + m] = f2b(a[1]);
            ylT[(b * 128 + i0 + 2) * 64 + m] = f2b(a[2]);
            ylT[(b * 128 + i0 + 3) * 64 + m] = f2b(a[3]);
        }
    }
    __syncthreads();
    // Lw / gb
#pragma unroll
    for (int r = 0; r < 16; ++r) {
        int idx = r * 256 + t;
        int i = idx >> 6, j = idx & 63;
        int gidx = b * 4096 + idx;
        float L = lk(sXs[j] + sYo[i]);
        Lw[gidx] = L;
        gb[gidx] = L + sEd[edge_mat[gidx]] + m_bias[gidx];
    }
}

// ---------------- K2: per (b,e) attention MFMA -> menT[b][e][j][c3]; pre copy fused
__global__ __launch_bounds__(256) void k_attn(const float* __restrict__ Lw,
                                              const u16* __restrict__ xfb, const u16* __restrict__ yfb,
                                              const float* __restrict__ xfT, const float* __restrict__ yfT,
                                              const int* __restrict__ path_mat, const float* __restrict__ p_bias,
                                              const float* __restrict__ ptab, const float* __restrict__ pconv,
                                              const float* __restrict__ pre, u16* __restrict__ menT) {
    int b = blockIdx.x >> 6, e = blockIdx.x & 63;
    int t = threadIdx.x;
    int lane = t & 63, w = t >> 6;
    __shared__ float sA[64][68];
    __shared__ u16 Abf[64][72];
    __shared__ u16 E2bf[64][72];
    __shared__ float sRed[256];
    __shared__ float sPdot[20];

    if (t < 20) {
        float s = 0.f;
        for (int d = 0; d < 32; ++d) s += ptab[t * 32 + d] * pconv[d];
        sPdot[t] = lk(s);
    }
    __syncthreads();

    {
        int m = t >> 2, n0 = (t & 3) * 16;
        int base = (((b * 64 + e) * 64 + m) * 64 + n0);
        const int4* pm4 = (const int4*)(path_mat + base);
        const float4* pb4 = (const float4*)(p_bias + base);
        const float4* L4 = (const float4*)(Lw + (b * 64 + m) * 64 + n0);
#pragma unroll
        for (int q = 0; q < 4; ++q) {
            int4 pm = pm4[q]; float4 pb = pb4[q]; float4 l = L4[q];
            float4 v;
            v.x = l.x + sPdot[pm.x] + pb.x;
            v.y = l.y + sPdot[pm.y] + pb.y;
            v.z = l.z + sPdot[pm.z] + pb.z;
            v.w = l.w + sPdot[pm.w] + pb.w;
            *(float4*)&sA[m][n0 + q * 4] = v;
        }
    }
    __syncthreads();

    if (t < 128) {
        int r = t >> 1, h = t & 1;
        const float4* rp = (const float4*)&sA[r][h * 32];
        float mx = -1e30f;
#pragma unroll
        for (int k = 0; k < 8; ++k) {
            float4 v = rp[k];
            mx = fmaxf(mx, fmaxf(fmaxf(v.x, v.y), fmaxf(v.z, v.w)));
        }
        mx = fmaxf(mx, __shfl_xor(mx, 1));
        float s = 0.f;
#pragma unroll
        for (int k = 0; k < 8; ++k) {
            float4 v = rp[k];
            s += __expf(v.x - mx) + __expf(v.y - mx) + __expf(v.z - mx) + __expf(v.w - mx);
        }
        s += __shfl_xor(s, 1);
        if (h == 0) { sRed[r] = mx; sRed[64 + r] = 1.f / s; }
    } else {
        int n = (t - 128) >> 1, h = t & 1;
        float mx = -1e30f;
#pragma unroll
        for (int k = 0; k < 32; ++k) mx = fmaxf(mx, sA[h * 32 + k][n]);
        mx = fmaxf(mx, __shfl_xor(mx, 1));
        float s = 0.f;
#pragma unroll
        for (int k = 0; k < 32; ++k) s += __expf(sA[h * 32 + k][n] - mx);
        s += __shfl_xor(s, 1);
        if (h == 0) { sRed[128 + n] = mx; sRed[192 + n] = 1.f / s; }
    }
    __syncthreads();

    {
        int m = t >> 2, q = t & 3;
        float rmax = sRed[m], rinv = sRed[64 + m];
        const float4* rp = (const float4*)&sA[m][q * 16];
#pragma unroll
        for (int g2 = 0; g2 < 2; ++g2) {
            float4 v0 = rp[g2 * 2], v1 = rp[g2 * 2 + 1];
            s16x8 pk;
            pk[0] = (short)f2b(__expf(v0.x - rmax) * rinv);
            pk[1] = (short)f2b(__expf(v0.y - rmax) * rinv);
            pk[2] = (short)f2b(__expf(v0.z - rmax) * rinv);
            pk[3] = (short)f2b(__expf(v0.w - rmax) * rinv);
            pk[4] = (short)f2b(__expf(v1.x - rmax) * rinv);
            pk[5] = (short)f2b(__expf(v1.y - rmax) * rinv);
            pk[6] = (short)f2b(__expf(v1.z - rmax) * rinv);
            pk[7] = (short)f2b(__expf(v1.w - rmax) * rinv);
            *(s16x8*)&Abf[m][q * 16 + g2 * 8] = pk;
        }
    }
    {
        int n = t >> 2, q = t & 3;
        float cmax = sRed[128 + n], cinv = sRed[192 + n];
#pragma unroll
        for (int g2 = 0; g2 < 2; ++g2) {
            s16x8 pk;
#pragma unroll
            for (int k = 0; k < 8; ++k) {
                float v = sA[q * 16 + g2 * 8 + k][n];
                pk[k] = (short)f2b(__expf(v - cmax) * cinv);
            }
            *(s16x8*)&E2bf[n][q * 16 + g2 * 8] = pk;
        }
    }
    __syncthreads();

    int l15 = lane & 15, q4 = lane >> 4;
    // GEMM1: xret[c][m]
    {
        f32x4 acc[2][4];
#pragma unroll
        for (int ci = 0; ci < 2; ++ci)
#pragma unroll
            for (int mt = 0; mt < 4; ++mt) acc[ci][mt] = (f32x4)(0.f);
#pragma unroll
        for (int kt = 0; kt < 2; ++kt) {
            s16x8 afr[2];
#pragma unroll
            for (int ci = 0; ci < 2; ++ci) {
                int c = (2 * w + ci) * 16 + l15;
                afr[ci] = *(const s16x8*)(yfb + (b * 128 + c) * 64 + kt * 32 + q4 * 8);
            }
            s16x8 bfr[4];
#pragma unroll
            for (int mt = 0; mt < 4; ++mt)
                bfr[mt] = *(const s16x8*)&Abf[mt * 16 + l15][kt * 32 + q4 * 8];
#pragma unroll
            for (int ci = 0; ci < 2; ++ci)
#pragma unroll
                for (int mt = 0; mt < 4; ++mt)
                    acc[ci][mt] = __builtin_amdgcn_mfma_f32_16x16x32_bf16(afr[ci], bfr[mt], acc[ci][mt], 0, 0, 0);
        }
#pragma unroll
        for (int ci = 0; ci < 2; ++ci) {
            int c0 = (2 * w + ci) * 16 + q4 * 4;
#pragma unroll
            for (int mt = 0; mt < 4; ++mt) {
                int m = mt * 16 + l15;
                float4 res = *(const float4*)(xfT + (b * 64 + m) * 128 + c0);
                f32x4 a = acc[ci][mt];
                u32 lo = (u32)f2b(lk(a[0] + res.x)) | ((u32)f2b(lk(a[1] + res.y)) << 16);
                u32 hi = (u32)f2b(lk(a[2] + res.z)) | ((u32)f2b(lk(a[3] + res.w)) << 16);
                *(uint2*)(menT + ((b * 64 + e) * 64 + m) * 384 + c0) = make_uint2(lo, hi);
            }
        }
    }
    // GEMM2: yret[c][n]
    {
        f32x4 acc[2][4];
#pragma unroll
        for (int ci = 0; ci < 2; ++ci)
#pragma unroll
            for (int nt = 0; nt < 4; ++nt) acc[ci][nt] = (f32x4)(0.f);
#pragma unroll
        for (int kt = 0; kt < 2; ++kt) {
            s16x8 afr[2];
#pragma unroll
            for (int ci = 0; ci < 2; ++ci) {
                int c = (2 * w + ci) * 16 + l15;
                afr[ci] = *(const s16x8*)(xfb + (b * 128 + c) * 64 + kt * 32 + q4 * 8);
            }
            s16x8 bfr[4];
#pragma unroll
            for (int nt = 0; nt < 4; ++nt)
                bfr[nt] = *(const s16x8*)&E2bf[nt * 16 + l15][kt * 32 + q4 * 8];
#pragma unroll
            for (int ci = 0; ci < 2; ++ci)
#pragma unroll
                for (int nt = 0; nt < 4; ++nt)
                    acc[ci][nt] = __builtin_amdgcn_mfma_f32_16x16x32_bf16(afr[ci], bfr[nt], acc[ci][nt], 0, 0, 0);
        }
#pragma unroll
        for (int ci = 0; ci < 2; ++ci) {
            int c0 = (2 * w + ci) * 16 + q4 * 4;
#pragma unroll
            for (int nt = 0; nt < 4; ++nt) {
                int n = nt * 16 + l15;
                float4 res = *(const float4*)(yfT + (b * 64 + n) * 128 + c0);
                f32x4 a = acc[ci][nt];
                u32 lo = (u32)f2b(lk(a[0] + res.x)) | ((u32)f2b(lk(a[1] + res.y)) << 16);
                u32 hi = (u32)f2b(lk(a[2] + res.z)) | ((u32)f2b(lk(a[3] + res.w)) << 16);
                *(uint2*)(menT + ((b * 64 + e) * 64 + n) * 384 + 128 + c0) = make_uint2(lo, hi);
            }
        }
    }
    // fused pre copy: menT[b][e][j][256+p]
    {
        int j = t & 63, pg = t >> 6;
#pragma unroll
        for (int oc = 0; oc < 4; ++oc) {
            int p0 = pg * 32 + oc * 8;
            s16x8 v;
#pragma unroll
            for (int k = 0; k < 8; ++k)
                v[k] = (short)f2b(pre[((b * 128 + p0 + k) * 64 + e) * 64 + j]);
            *(s16x8*)(menT + ((b * 64 + e) * 64 + j) * 384 + 256 + p0) = v;
        }
    }
}

// ---------------- K3: conv1 (1x1, 384->128) MFMA, no LDS (unchanged R4)
__global__ __launch_bounds__(256) void k_conv1(const u16* __restrict__ menT, const u16* __restrict__ wA1,
                                               const float* __restrict__ b1, u16* __restrict__ hT) {
    int b = blockIdx.x >> 6, i = blockIdx.x & 63;
    int t = threadIdx.x;
    int lane = t & 63, w = t >> 6, wm = w & 1, wn = w >> 1;
    int l15 = lane & 15, q4 = lane >> 4;

    f32x4 acc[4][2];
#pragma unroll
    for (int mt = 0; mt < 4; ++mt)
#pragma unroll
        for (int nt = 0; nt < 2; ++nt) acc[mt][nt] = (f32x4)(0.f);

    const u16* mrow = menT + (b * 64 + i) * 64 * 384;
    for (int kc = 0; kc < 12; ++kc) {
        s16x8 af[4];
#pragma unroll
        for (int mt = 0; mt < 4; ++mt)
            af[mt] = *(const s16x8*)(wA1 + (((kc * 8 + wm * 4 + mt) * 64 + lane) << 3));
        s16x8 bf[2];
#pragma unroll
        for (int nt = 0; nt < 2; ++nt) {
            int j = (wn * 2 + nt) * 16 + l15;
            bf[nt] = *(const s16x8*)(mrow + j * 384 + kc * 32 + q4 * 8);
        }
#pragma unroll
        for (int mt = 0; mt < 4; ++mt)
#pragma unroll
            for (int nt = 0; nt < 2; ++nt)
                acc[mt][nt] = __builtin_amdgcn_mfma_f32_16x16x32_bf16(af[mt], bf[nt], acc[mt][nt], 0, 0, 0);
    }

#pragma unroll
    for (int mt = 0; mt < 4; ++mt) {
        int o0 = (wm * 4 + mt) * 16 + q4 * 4;
        float4 bb = *(const float4*)(b1 + o0);
#pragma unroll
        for (int nt = 0; nt < 2; ++nt) {
            int j = (wn * 2 + nt) * 16 + l15;
            f32x4 a = acc[mt][nt];
            u32 lo = (u32)f2b(lk(a[0] + bb.x)) | ((u32)f2b(lk(a[1] + bb.y)) << 16);
            u32 hi = (u32)f2b(lk(a[2] + bb.z)) | ((u32)f2b(lk(a[3] + bb.w)) << 16);
            *(uint2*)(hT + ((b * 64 + i) * 64 + j) * 128 + o0) = make_uint2(lo, hi);
        }
    }
}

// ---------------- K4: conv2 (3x3 SAME) MFMA, 1 row/block (512 blocks), fused scores -> g
__global__ __launch_bounds__(256) void k_conv2(const u16* __restrict__ hT, const u16* __restrict__ wA2,
                                               const float* __restrict__ b2, const float* __restrict__ score_w,
                                               const float* __restrict__ gb, float* __restrict__ m2r,
                                               float* __restrict__ g) {
    int b = blockIdx.x >> 6, i = blockIdx.x & 63;
    int t = threadIdx.x;
    int lane = t & 63, w = t >> 6, wm = w & 1, wn = w >> 1;
    int l15 = lane & 15, q4 = lane >> 4;
    __shared__ u16 sB2[3][66][136];   // rows i-1..i+1, halo j cols 0 & 65
    __shared__ float sSc[2][64];

    // zero halo cols
#pragma unroll
    for (int q = 0; q < 2; ++q) {
        int u = q * 256 + t;
        if (u < 384) {
            int r = u >> 7, rem = u & 127, hcol = rem >> 6, c2 = rem & 63;
            *(u32*)&sB2[r][hcol ? 65 : 0][c2 * 2] = 0u;
        }
    }
    // stage 3 rows
#pragma unroll
    for (int it = 0; it < 12; ++it) {
        int u = it * 256 + t;
        int cg = u & 15, j = (u >> 4) & 63, r = u >> 10;
        int ir = i - 1 + r;
        int4 v = make_int4(0, 0, 0, 0);
        if (ir >= 0 && ir < 64)
            v = *(const int4*)(hT + ((b * 64 + ir) * 64 + j) * 128 + cg * 8);
        *(int4*)&sB2[r][j + 1][cg * 8] = v;
    }
    __syncthreads();

    f32x4 acc[4][2];
#pragma unroll
    for (int mt = 0; mt < 4; ++mt)
#pragma unroll
        for (int nt = 0; nt < 2; ++nt) acc[mt][nt] = (f32x4)(0.f);

    for (int kc = 0; kc < 4; ++kc) {
#pragma unroll
        for (int tap = 0; tap < 9; ++tap) {
            int di = tap / 3, dj = tap % 3;
            s16x8 af[4];
#pragma unroll
            for (int mt = 0; mt < 4; ++mt)
                af[mt] = *(const s16x8*)(wA2 + ((((tap * 4 + kc) * 8 + wm * 4 + mt) * 64 + lane) << 3));
#pragma unroll
            for (int nt = 0; nt < 2; ++nt) {
                int jin = wn * 32 + nt * 16 + l15 + dj;   // 0..65 in halo frame
                s16x8 bf = *(const s16x8*)(&sB2[di][jin][kc * 32 + q4 * 8]);
#pragma unroll
                for (int mt = 0; mt < 4; ++mt)
                    acc[mt][nt] = __builtin_amdgcn_mfma_f32_16x16x32_bf16(af[mt], bf, acc[mt][nt], 0, 0, 0);
            }
        }
    }

    float part[2] = {0.f, 0.f};
#pragma unroll
    for (int mt = 0; mt < 4; ++mt) {
        int o0 = wm * 64 + mt * 16 + q4 * 4;
        float4 bb = *(const float4*)(b2 + o0);
        float4 sw = *(const float4*)(score_w + o0);
#pragma unroll
        for (int nt = 0; nt < 2; ++nt) {
            int j = wn * 32 + nt * 16 + l15;
            f32x4 a = acc[mt][nt];
            float v0 = lk(a[0] + bb.x), v1 = lk(a[1] + bb.y);
            float v2 = lk(a[2] + bb.z), v3 = lk(a[3] + bb.w);
            float* dst = m2r + ((b * 128 + o0) * 64 + i) * 64 + j;
            dst[0] = v0; dst[4096] = v1; dst[8192] = v2; dst[12288] = v3;
            part[nt] += sw.x * v0 + sw.y * v1 + sw.z * v2 + sw.w * v3;
        }
    }
#pragma unroll
    for (int nt = 0; nt < 2; ++nt) {
        float p = part[nt];
        p += __shfl_xor(p, 16);
        p += __shfl_xor(p, 32);
        if (q4 == 0) sSc[wm][wn * 32 + nt * 16 + l15] = p;
    }
    __syncthreads();
    if (t < 64) {
        float s = sSc[0][t] + sSc[1][t];
        int gi = (b * 64 + i) * 64 + t;
        g[gi] = gb[gi] + lk(s);
    }
}

// ---------------- K5: final dual softmax + MFMA GEMMs + residual. One block per b.
__global__ __launch_bounds__(256) void k_gout(const float* __restrict__ g,
                                              const u16* __restrict__ xlT, const u16* __restrict__ ylT,
                                              const float* __restrict__ x, const float* __restrict__ y,
                                              float* __restrict__ out) {
    int b = blockIdx.x;
    int t = threadIdx.x;
    int lane = t & 63, w = t >> 6, l15 = lane & 15, q4 = lane >> 4;
    __shared__ float sG[64][68];
    __shared__ u16 Gbf[64][72];    // row-softmax [m][n]
    __shared__ u16 G2bf[64][72];   // col-softmax [n][m]
    __shared__ float sRed[256];

    // load g[b]
#pragma unroll
    for (int r = 0; r < 16; ++r) {
        int idx = r * 256 + t;
        sG[idx >> 6][idx & 63] = g[b * 4096 + idx];
    }
    __syncthreads();

    if (t < 128) {
        int r = t >> 1, h = t & 1;
        const float4* rp = (const float4*)&sG[r][h * 32];
        float mx = -1e30f;
#pragma unroll
        for (int k = 0; k < 8; ++k) {
            float4 v = rp[k];
            mx = fmaxf(mx, fmaxf(fmaxf(v.x, v.y), fmaxf(v.z, v.w)));
        }
        mx = fmaxf(mx, __shfl_xor(mx, 1));
        float s = 0.f;
#pragma unroll
        for (int k = 0; k < 8; ++k) {
            float4 v = rp[k];
            s += __expf(v.x - mx) + __expf(v.y - mx) + __expf(v.z - mx) + __expf(v.w - mx);
        }
        s += __shfl_xor(s, 1);
        if (h == 0) { sRed[r] = mx; sRed[64 + r] = 1.f / s; }
    } else {
        int n = (t - 128) >> 1, h = t & 1;
        float mx = -1e30f;
#pragma unroll
        for (int k = 0; k < 32; ++k) mx = fmaxf(mx, sG[h * 32 + k][n]);
        mx = fmaxf(mx, __shfl_xor(mx, 1));
        float s = 0.f;
#pragma unroll
        for (int k = 0; k < 32; ++k) s += __expf(sG[h * 32 + k][n] - mx);
        s += __shfl_xor(s, 1);
        if (h == 0) { sRed[128 + n] = mx; sRed[192 + n] = 1.f / s; }
    }
    __syncthreads();

    {
        int m = t >> 2, q = t & 3;
        float rmax = sRed[m], rinv = sRed[64 + m];
        const float4* rp = (const float4*)&sG[m][q * 16];
#pragma unroll
        for (int g2 = 0; g2 < 2; ++g2) {
            float4 v0 = rp[g2 * 2], v1 = rp[g2 * 2 + 1];
            s16x8 pk;
            pk[0] = (short)f2b(__expf(v0.x - rmax) * rinv);
            pk[1] = (short)f2b(__expf(v0.y - rmax) * rinv);
            pk[2] = (short)f2b(__expf(v0.z - rmax) * rinv);
            pk[3] = (short)f2b(__expf(v0.w - rmax) * rinv);
            pk[4] = (short)f2b(__expf(v1.x - rmax) * rinv);
            pk[5] = (short)f2b(__expf(v1.y - rmax) * rinv);
            pk[6] = (short)f2b(__expf(v1.z - rmax) * rinv);
            pk[7] = (short)f2b(__expf(v1.w - rmax) * rinv);
            *(s16x8*)&Gbf[m][q * 16 + g2 * 8] = pk;
        }
    }
    {
        int n = t >> 2, q = t & 3;
        float cmax = sRed[128 + n], cinv = sRed[192 + n];
#pragma unroll
        for (int g2 = 0; g2 < 2; ++g2) {
            s16x8 pk;
#pragma unroll
            for (int k = 0; k < 8; ++k) {
                float v = sG[q * 16 + g2 * 8 + k][n];
                pk[k] = (short)f2b(__expf(v - cmax) * cinv);
            }
            *(s16x8*)&G2bf[n][q * 16 + g2 * 8] = pk;
        }
    }
    __syncthreads();

    int mcol = w * 16 + l15;   // this wave's output column
    // GEMM1: out_x[i][m] = sum_n G[m][n] ylT[i][n] + x[i][m]
    {
        f32x4 acc[8];
#pragma unroll
        for (int mt = 0; mt < 8; ++mt) acc[mt] = (f32x4)(0.f);
#pragma unroll
        for (int kt = 0; kt < 2; ++kt) {
            s16x8 bfr = *(const s16x8*)&Gbf[mcol][kt * 32 + q4 * 8];
#pragma unroll
            for (int mt = 0; mt < 8; ++mt) {
                s16x8 af = *(const s16x8*)(ylT + (b * 128 + mt * 16 + l15) * 64 + kt * 32 + q4 * 8);
                acc[mt] = __builtin_amdgcn_mfma_f32_16x16x32_bf16(af, bfr, acc[mt], 0, 0, 0);
            }
        }
#pragma unroll
        for (int mt = 0; mt < 8; ++mt) {
            int i0 = mt * 16 + q4 * 4;
            f32x4 a = acc[mt];
#pragma unroll
            for (int r = 0; r < 4; ++r) {
                int ad = (b * 128 + i0 + r) * 64 + mcol;
                out[ad] = a[r] + x[ad];
            }
        }
    }
    // GEMM2: out_y[i][n] = sum_m G2[n][m] xlT[i][m] + y[i][n]
    {
        f32x4 acc[8];
#pragma unroll
        for (int mt = 0; mt < 8; ++mt) acc[mt] = (f32x4)(0.f);
#pragma unroll
        for (int kt = 0; kt < 2; ++kt) {
            s16x8 bfr = *(const s16x8*)&G2bf[mcol][kt * 32 + q4 * 8];
#pragma unroll
            for (int mt = 0; mt < 8; ++mt) {
                s16x8 af = *(const s16x8*)(xlT + (b * 128 + mt * 16 + l15) * 64 + kt * 32 + q4 * 8);
                acc[mt] = __builtin_amdgcn_mfma_f32_16x16x32_bf16(af, bfr, acc[mt], 0, 0, 0);
            }
        }
#pragma unroll
        for (int mt = 0; mt < 8; ++mt) {
            int i0 = mt * 16 + q4 * 4;
            f32x4 a = acc[mt];
#pragma unroll
            for (int r = 0; r < 4; ++r) {
                int ad = (b * 128 + i0 + r) * 64 + mcol;
                out[65536 + ad] = a[r] + y[ad];
            }
        }
    }
}

extern "C" void kernel_launch(void* const* d_in, const int* in_sizes, int n_in,
                              void* d_out, int out_size, void* d_ws, size_t ws_size,
                              hipStream_t stream) {
    const float* x = (const float*)d_in[0];
    const float* y = (const float*)d_in[1];
    const float* m_bias = (const float*)d_in[2];
    const int* edge_mat = (const int*)d_in[3];
    const float* p_bias = (const float*)d_in[4];
    const int* path_mat = (const int*)d_in[5];
    const float* pre = (const float*)d_in[6];
    const float* xc1 = (const float*)d_in[7];
    const float* yc1 = (const float*)d_in[8];
    const float* xc2w = (const float*)d_in[9];
    const float* xc2b = (const float*)d_in[10];
    const float* yc2w = (const float*)d_in[11];
    const float* yc2b = (const float*)d_in[12];
    const float* pconv = (const float*)d_in[13];
    const float* econv = (const float*)d_in[14];
    const float* w1 = (const float*)d_in[15];
    const float* b1 = (const float*)d_in[16];
    const float* w2 = (const float*)d_in[17];
    const float* b2 = (const float*)d_in[18];
    const float* score_w = (const float*)d_in[19];
    const float* xlw = (const float*)d_in[20];
    const float* ylw = (const float*)d_in[21];
    const float* etab = (const float*)d_in[22];
    const float* ptab = (const float*)d_in[23];

    float* Lw = (float*)d_ws;               // 32768 f
    float* gb = Lw + 32768;
    float* g = gb + 32768;
    float* xfT = g + 32768;                 // 65536 f
    float* yfT = xfT + 65536;
    u16* wA1 = (u16*)(yfT + 65536);         // 49152 u16
    u16* wA2 = wA1 + 49152;                 // 147456 u16
    u16* xfb = wA2 + 147456;                // 65536 u16
    u16* yfb = xfb + 65536;
    u16* xlT = yfb + 65536;
    u16* ylT = xlT + 65536;
    u16* menT = ylT + 65536;                // 12582912 u16
    u16* hT = menT + 12582912;              // 4194304 u16

    float* out = (float*)d_out;
    float* out_m2r = out + 131072;

    hipLaunchKernelGGL(k_prepw, dim3(768), dim3(256), 0, stream, w1, w2, wA1, wA2);
    hipLaunchKernelGGL(k_front, dim3(8), dim3(256), 0, stream, x, y, xc1, yc1, xc2w, xc2b,
                       yc2w, yc2b, xlw, ylw, etab, econv, edge_mat, m_bias,
                       xfb, yfb, xfT, yfT, xlT, ylT, Lw, gb);
    hipLaunchKernelGGL(k_attn, dim3(512), dim3(256), 0, stream, Lw, xfb, yfb, xfT, yfT,
                       path_mat, p_bias, ptab, pconv, pre, menT);
    hipLaunchKernelGGL(k_conv1, dim3(512), dim3(256), 0, stream, menT, wA1, b1, hT);
    hipLaunchKernelGGL(k_conv2, dim3(512), dim3(256), 0, stream, hT, wA2, b2, score_w, gb,
                       out_m2r, g);
    hipLaunchKernelGGL(k_gout, dim3(8), dim3(256), 0, stream, g, xlT, ylT, x, y, out);
}

// Round 6
// 190.484 us; speedup vs baseline: 1.1499x; 1.1499x over previous
//
#include <hip/hip_runtime.h>
#include <hip/hip_bf16.h>

// B=8, E=64, CIN=C=PRE=128. fp32 I/O; bf16 MFMA everywhere GEMM-shaped.

typedef unsigned short u16;
typedef unsigned int u32;
typedef short s16x8 __attribute__((ext_vector_type(8)));
typedef float f32x4 __attribute__((ext_vector_type(4)));

__device__ __forceinline__ float b2f(u16 u) { return __uint_as_float(((u32)u) << 16); }
__device__ __forceinline__ u16 f2b(float f) {
    u32 x = __float_as_uint(f);
    u32 r = (x + 0x7fffu + ((x >> 16) & 1u)) >> 16;   // RNE
    return (u16)r;
}
__device__ __forceinline__ float lk(float v) { return v >= 0.f ? v : 0.1f * v; }
__device__ __forceinline__ s16x8 cvt8(const float* p) {
    float4 a = ((const float4*)p)[0], c = ((const float4*)p)[1];
    s16x8 r;
    r[0] = (short)f2b(a.x); r[1] = (short)f2b(a.y); r[2] = (short)f2b(a.z); r[3] = (short)f2b(a.w);
    r[4] = (short)f2b(c.x); r[5] = (short)f2b(c.y); r[6] = (short)f2b(c.z); r[7] = (short)f2b(c.w);
    return r;
}

// ---------------- K1: merged prep. blocks [0,768): weight frag prep;
// [768,800): front GEMMs (b x type); [800,1312): pre -> menT transpose.
__global__ __launch_bounds__(256) void k_prep(const float* __restrict__ w1, const float* __restrict__ w2,
                                              u16* __restrict__ wA1, u16* __restrict__ wA2,
                                              const float* __restrict__ x, const float* __restrict__ y,
                                              const float* __restrict__ xc1, const float* __restrict__ yc1,
                                              const float* __restrict__ xc2w, const float* __restrict__ xc2b,
                                              const float* __restrict__ yc2w, const float* __restrict__ yc2b,
                                              const float* __restrict__ xlw, const float* __restrict__ ylw,
                                              u16* __restrict__ xfb, u16* __restrict__ yfb,
                                              float* __restrict__ xfT, float* __restrict__ yfT,
                                              u16* __restrict__ xlT, u16* __restrict__ ylT,
                                              float* __restrict__ Xs, float* __restrict__ Yo,
                                              const float* __restrict__ pre, u16* __restrict__ menT) {
    int bid = blockIdx.x;
    int t = threadIdx.x;
    if (bid < 768) {
        int idx = bid * 256 + t;
        if (idx < 49152) {
            int e = idx & 7, lane = (idx >> 3) & 63, mtg = (idx >> 9) & 7, kc = idx >> 12;
            int o = mtg * 16 + (lane & 15), c = kc * 32 + ((lane >> 4) << 3) + e;
            wA1[idx] = f2b(w1[o * 384 + c]);
        } else {
            int id2 = idx - 49152;
            if (id2 < 147456) {
                int e = id2 & 7, lane = (id2 >> 3) & 63, mtg = (id2 >> 9) & 7;
                int kc = (id2 >> 12) & 3, tap = id2 >> 14;
                int o = mtg * 16 + (lane & 15), c = kc * 32 + ((lane >> 4) << 3) + e;
                wA2[id2] = f2b(w2[(o * 128 + c) * 9 + tap]);
            }
        }
        return;
    }
    if (bid < 800) {
        int r = bid - 768;
        int b = r >> 2, g4 = r & 3;
        int lane = t & 63, w = t >> 6, l15 = lane & 15, q4 = lane >> 4;
        __shared__ u16 sT[64][136];
        const float* src = (g4 == 0 || g4 == 2) ? x : y;
        const float* wptr = (g4 == 0) ? xc1 : (g4 == 1) ? yc1 : (g4 == 2) ? xlw : ylw;
        {
            int i = t >> 1, m0 = (t & 1) * 32;
            const float4* ps = (const float4*)(src + (b * 128 + i) * 64 + m0);
#pragma unroll
            for (int q = 0; q < 8; ++q) {
                float4 v = ps[q];
                int m = m0 + q * 4;
                sT[m + 0][i] = f2b(v.x); sT[m + 1][i] = f2b(v.y);
                sT[m + 2][i] = f2b(v.z); sT[m + 3][i] = f2b(v.w);
            }
        }
        __syncthreads();
        int m = w * 16 + l15;
        f32x4 acc[8];
#pragma unroll
        for (int mt = 0; mt < 8; ++mt) acc[mt] = (f32x4)(0.f);
#pragma unroll
        for (int kt = 0; kt < 4; ++kt) {
            s16x8 bfr = *(const s16x8*)&sT[m][kt * 32 + q4 * 8];
#pragma unroll
            for (int mt = 0; mt < 8; ++mt) {
                s16x8 af = cvt8(wptr + (mt * 16 + l15) * 128 + kt * 32 + q4 * 8);
                acc[mt] = __builtin_amdgcn_mfma_f32_16x16x32_bf16(af, bfr, acc[mt], 0, 0, 0);
            }
        }
        if (g4 == 0 || g4 == 1) {
            u16* fb = (g4 == 0) ? xfb : yfb;
            float* fT = (g4 == 0) ? xfT : yfT;
            const float* c2w = (g4 == 0) ? xc2w : yc2w;
            const float* c2b = (g4 == 0) ? xc2b : yc2b;
            float* dvec = (g4 == 0) ? Xs : Yo;
            float sp = 0.f;
#pragma unroll
            for (int mt = 0; mt < 8; ++mt) {
                int c0 = mt * 16 + q4 * 4;
                f32x4 a = acc[mt];
                fb[(b * 128 + c0 + 0) * 64 + m] = f2b(a[0]);
                fb[(b * 128 + c0 + 1) * 64 + m] = f2b(a[1]);
                fb[(b * 128 + c0 + 2) * 64 + m] = f2b(a[2]);
                fb[(b * 128 + c0 + 3) * 64 + m] = f2b(a[3]);
                *(float4*)(fT + (b * 64 + m) * 128 + c0) = make_float4(a[0], a[1], a[2], a[3]);
                float4 wv = *(const float4*)(c2w + c0);
                sp += wv.x * a[0] + wv.y * a[1] + wv.z * a[2] + wv.w * a[3];
            }
            sp += __shfl_xor(sp, 16);
            sp += __shfl_xor(sp, 32);
            if (q4 == 0) dvec[b * 64 + m] = sp + c2b[0];
        } else {
            u16* lT = (g4 == 2) ? xlT : ylT;
#pragma unroll
            for (int mt = 0; mt < 8; ++mt) {
                int i0 = mt * 16 + q4 * 4;
                f32x4 a = acc[mt];
                lT[(b * 128 + i0 + 0) * 64 + m] = f2b(a[0]);
                lT[(b * 128 + i0 + 1) * 64 + m] = f2b(a[1]);
                lT[(b * 128 + i0 + 2) * 64 + m] = f2b(a[2]);
                lT[(b * 128 + i0 + 3) * 64 + m] = f2b(a[3]);
            }
        }
        return;
    }
    {
        int r = bid - 800;
        int b = r >> 6, i = r & 63;
        int j = t & 63, pg = t >> 6;
#pragma unroll
        for (int oc = 0; oc < 4; ++oc) {
            int p0 = pg * 32 + oc * 8;
            s16x8 v;
#pragma unroll
            for (int k = 0; k < 8; ++k)
                v[k] = (short)f2b(pre[((b * 128 + p0 + k) * 64 + i) * 64 + j]);
            *(s16x8*)(menT + ((b * 64 + i) * 64 + j) * 384 + 256 + p0) = v;
        }
    }
}

// ---------------- K2: per (b,e) attention MFMA -> menT[b][e][j][c3<256]
__global__ __launch_bounds__(256) void k_attn(const float* __restrict__ Xs, const float* __restrict__ Yo,
                                              const u16* __restrict__ xfb, const u16* __restrict__ yfb,
                                              const float* __restrict__ xfT, const float* __restrict__ yfT,
                                              const int* __restrict__ path_mat, const float* __restrict__ p_bias,
                                              const float* __restrict__ ptab, const float* __restrict__ pconv,
                                              u16* __restrict__ menT) {
    int b = blockIdx.x >> 6, e = blockIdx.x & 63;
    int t = threadIdx.x;
    int lane = t & 63, w = t >> 6;
    __shared__ float sA[64][68];
    __shared__ u16 Abf[64][72];
    __shared__ u16 E2bf[64][72];
    __shared__ float sRed[256];
    __shared__ float sPdot[20];
    __shared__ float sXv[64], sYv[64];

    if (t < 20) {
        float s = 0.f;
        for (int d = 0; d < 32; ++d) s += ptab[t * 32 + d] * pconv[d];
        sPdot[t] = lk(s);
    } else if (t >= 64 && t < 128) {
        sXv[t - 64] = Xs[b * 64 + t - 64];
    } else if (t >= 128 && t < 192) {
        sYv[t - 128] = Yo[b * 64 + t - 128];
    }
    __syncthreads();

    {
        int m = t >> 2, n0 = (t & 3) * 16;
        int base = (((b * 64 + e) * 64 + m) * 64 + n0);
        const int4* pm4 = (const int4*)(path_mat + base);
        const float4* pb4 = (const float4*)(p_bias + base);
        float yom = sYv[m];
#pragma unroll
        for (int q = 0; q < 4; ++q) {
            int4 pm = pm4[q]; float4 pb = pb4[q];
            int n = n0 + q * 4;
            float4 v;
            v.x = lk(sXv[n + 0] + yom) + sPdot[pm.x] + pb.x;
            v.y = lk(sXv[n + 1] + yom) + sPdot[pm.y] + pb.y;
            v.z = lk(sXv[n + 2] + yom) + sPdot[pm.z] + pb.z;
            v.w = lk(sXv[n + 3] + yom) + sPdot[pm.w] + pb.w;
            *(float4*)&sA[m][n] = v;
        }
    }
    __syncthreads();

    if (t < 128) {
        int r = t >> 1, h = t & 1;
        const float4* rp = (const float4*)&sA[r][h * 32];
        float mx = -1e30f;
#pragma unroll
        for (int k = 0; k < 8; ++k) {
            float4 v = rp[k];
            mx = fmaxf(mx, fmaxf(fmaxf(v.x, v.y), fmaxf(v.z, v.w)));
        }
        mx = fmaxf(mx, __shfl_xor(mx, 1));
        float s = 0.f;
#pragma unroll
        for (int k = 0; k < 8; ++k) {
            float4 v = rp[k];
            s += __expf(v.x - mx) + __expf(v.y - mx) + __expf(v.z - mx) + __expf(v.w - mx);
        }
        s += __shfl_xor(s, 1);
        if (h == 0) { sRed[r] = mx; sRed[64 + r] = 1.f / s; }
    } else {
        int n = (t - 128) >> 1, h = t & 1;
        float mx = -1e30f;
#pragma unroll
        for (int k = 0; k < 32; ++k) mx = fmaxf(mx, sA[h * 32 + k][n]);
        mx = fmaxf(mx, __shfl_xor(mx, 1));
        float s = 0.f;
#pragma unroll
        for (int k = 0; k < 32; ++k) s += __expf(sA[h * 32 + k][n] - mx);
        s += __shfl_xor(s, 1);
        if (h == 0) { sRed[128 + n] = mx; sRed[192 + n] = 1.f / s; }
    }
    __syncthreads();

    {
        int m = t >> 2, q = t & 3;
        float rmax = sRed[m], rinv = sRed[64 + m];
        const float4* rp = (const float4*)&sA[m][q * 16];
#pragma unroll
        for (int g2 = 0; g2 < 2; ++g2) {
            float4 v0 = rp[g2 * 2], v1 = rp[g2 * 2 + 1];
            s16x8 pk;
            pk[0] = (short)f2b(__expf(v0.x - rmax) * rinv);
            pk[1] = (short)f2b(__expf(v0.y - rmax) * rinv);
            pk[2] = (short)f2b(__expf(v0.z - rmax) * rinv);
            pk[3] = (short)f2b(__expf(v0.w - rmax) * rinv);
            pk[4] = (short)f2b(__expf(v1.x - rmax) * rinv);
            pk[5] = (short)f2b(__expf(v1.y - rmax) * rinv);
            pk[6] = (short)f2b(__expf(v1.z - rmax) * rinv);
            pk[7] = (short)f2b(__expf(v1.w - rmax) * rinv);
            *(s16x8*)&Abf[m][q * 16 + g2 * 8] = pk;
        }
    }
    {
        int n = t >> 2, q = t & 3;
        float cmax = sRed[128 + n], cinv = sRed[192 + n];
#pragma unroll
        for (int g2 = 0; g2 < 2; ++g2) {
            s16x8 pk;
#pragma unroll
            for (int k = 0; k < 8; ++k) {
                float v = sA[q * 16 + g2 * 8 + k][n];
                pk[k] = (short)f2b(__expf(v - cmax) * cinv);
            }
            *(s16x8*)&E2bf[n][q * 16 + g2 * 8] = pk;
        }
    }
    __syncthreads();

    int l15 = lane & 15, q4 = lane >> 4;
    // GEMM1: xret[c][m] = lk(sum_n A[m][n] yf[c][n] + xf[c][m])
    {
        f32x4 acc[2][4];
#pragma unroll
        for (int ci = 0; ci < 2; ++ci)
#pragma unroll
            for (int mt = 0; mt < 4; ++mt) acc[ci][mt] = (f32x4)(0.f);
#pragma unroll
        for (int kt = 0; kt < 2; ++kt) {
            s16x8 afr[2];
#pragma unroll
            for (int ci = 0; ci < 2; ++ci) {
                int c = (2 * w + ci) * 16 + l15;
                afr[ci] = *(const s16x8*)(yfb + (b * 128 + c) * 64 + kt * 32 + q4 * 8);
            }
            s16x8 bfr[4];
#pragma unroll
            for (int mt = 0; mt < 4; ++mt)
                bfr[mt] = *(const s16x8*)&Abf[mt * 16 + l15][kt * 32 + q4 * 8];
#pragma unroll
            for (int ci = 0; ci < 2; ++ci)
#pragma unroll
                for (int mt = 0; mt < 4; ++mt)
                    acc[ci][mt] = __builtin_amdgcn_mfma_f32_16x16x32_bf16(afr[ci], bfr[mt], acc[ci][mt], 0, 0, 0);
        }
#pragma unroll
        for (int ci = 0; ci < 2; ++ci) {
            int c0 = (2 * w + ci) * 16 + q4 * 4;
#pragma unroll
            for (int mt = 0; mt < 4; ++mt) {
                int m = mt * 16 + l15;
                float4 res = *(const float4*)(xfT + (b * 64 + m) * 128 + c0);
                f32x4 a = acc[ci][mt];
                u32 lo = (u32)f2b(lk(a[0] + res.x)) | ((u32)f2b(lk(a[1] + res.y)) << 16);
                u32 hi = (u32)f2b(lk(a[2] + res.z)) | ((u32)f2b(lk(a[3] + res.w)) << 16);
                *(uint2*)(menT + ((b * 64 + e) * 64 + m) * 384 + c0) = make_uint2(lo, hi);
            }
        }
    }
    // GEMM2: yret[c][n] = lk(sum_m E2'[n][m] xf[c][m] + yf[c][n])
    {
        f32x4 acc[2][4];
#pragma unroll
        for (int ci = 0; ci < 2; ++ci)
#pragma unroll
            for (int nt = 0; nt < 4; ++nt) acc[ci][nt] = (f32x4)(0.f);
#pragma unroll
        for (int kt = 0; kt < 2; ++kt) {
            s16x8 afr[2];
#pragma unroll
            for (int ci = 0; ci < 2; ++ci) {
                int c = (2 * w + ci) * 16 + l15;
                afr[ci] = *(const s16x8*)(xfb + (b * 128 + c) * 64 + kt * 32 + q4 * 8);
            }
            s16x8 bfr[4];
#pragma unroll
            for (int nt = 0; nt < 4; ++nt)
                bfr[nt] = *(const s16x8*)&E2bf[nt * 16 + l15][kt * 32 + q4 * 8];
#pragma unroll
            for (int ci = 0; ci < 2; ++ci)
#pragma unroll
                for (int nt = 0; nt < 4; ++nt)
                    acc[ci][nt] = __builtin_amdgcn_mfma_f32_16x16x32_bf16(afr[ci], bfr[nt], acc[ci][nt], 0, 0, 0);
        }
#pragma unroll
        for (int ci = 0; ci < 2; ++ci) {
            int c0 = (2 * w + ci) * 16 + q4 * 4;
#pragma unroll
            for (int nt = 0; nt < 4; ++nt) {
                int n = nt * 16 + l15;
                float4 res = *(const float4*)(yfT + (b * 64 + n) * 128 + c0);
                f32x4 a = acc[ci][nt];
                u32 lo = (u32)f2b(lk(a[0] + res.x)) | ((u32)f2b(lk(a[1] + res.y)) << 16);
                u32 hi = (u32)f2b(lk(a[2] + res.z)) | ((u32)f2b(lk(a[3] + res.w)) << 16);
                *(uint2*)(menT + ((b * 64 + e) * 64 + n) * 384 + 128 + c0) = make_uint2(lo, hi);
            }
        }
    }
}

// ---------------- K3: conv1 (1x1, 384->128) MFMA, no LDS
__global__ __launch_bounds__(256) void k_conv1(const u16* __restrict__ menT, const u16* __restrict__ wA1,
                                               const float* __restrict__ b1, u16* __restrict__ hT) {
    int b = blockIdx.x >> 6, i = blockIdx.x & 63;
    int t = threadIdx.x;
    int lane = t & 63, w = t >> 6, wm = w & 1, wn = w >> 1;
    int l15 = lane & 15, q4 = lane >> 4;

    f32x4 acc[4][2];
#pragma unroll
    for (int mt = 0; mt < 4; ++mt)
#pragma unroll
        for (int nt = 0; nt < 2; ++nt) acc[mt][nt] = (f32x4)(0.f);

    const u16* mrow = menT + (b * 64 + i) * 64 * 384;
    for (int kc = 0; kc < 12; ++kc) {
        s16x8 af[4];
#pragma unroll
        for (int mt = 0; mt < 4; ++mt)
            af[mt] = *(const s16x8*)(wA1 + (((kc * 8 + wm * 4 + mt) * 64 + lane) << 3));
        s16x8 bf[2];
#pragma unroll
        for (int nt = 0; nt < 2; ++nt) {
            int j = (wn * 2 + nt) * 16 + l15;
            bf[nt] = *(const s16x8*)(mrow + j * 384 + kc * 32 + q4 * 8);
        }
#pragma unroll
        for (int mt = 0; mt < 4; ++mt)
#pragma unroll
            for (int nt = 0; nt < 2; ++nt)
                acc[mt][nt] = __builtin_amdgcn_mfma_f32_16x16x32_bf16(af[mt], bf[nt], acc[mt][nt], 0, 0, 0);
    }

#pragma unroll
    for (int mt = 0; mt < 4; ++mt) {
        int o0 = (wm * 4 + mt) * 16 + q4 * 4;
        float4 bb = *(const float4*)(b1 + o0);
#pragma unroll
        for (int nt = 0; nt < 2; ++nt) {
            int j = (wn * 2 + nt) * 16 + l15;
            f32x4 a = acc[mt][nt];
            u32 lo = (u32)f2b(lk(a[0] + bb.x)) | ((u32)f2b(lk(a[1] + bb.y)) << 16);
            u32 hi = (u32)f2b(lk(a[2] + bb.z)) | ((u32)f2b(lk(a[3] + bb.w)) << 16);
            *(uint2*)(hT + ((b * 64 + i) * 64 + j) * 128 + o0) = make_uint2(lo, hi);
        }
    }
}

// ---------------- K4: conv2 (3x3 SAME) MFMA + fused scores + inline gbase -> g
__global__ __launch_bounds__(256) void k_conv2(const u16* __restrict__ hT, const u16* __restrict__ wA2,
                                               const float* __restrict__ b2, const float* __restrict__ score_w,
                                               const float* __restrict__ Xs, const float* __restrict__ Yo,
                                               const float* __restrict__ etab, const float* __restrict__ econv,
                                               const int* __restrict__ edge_mat, const float* __restrict__ m_bias,
                                               float* __restrict__ m2r, float* __restrict__ g) {
    int b = blockIdx.x >> 6, i = blockIdx.x & 63;
    int t = threadIdx.x;
    int lane = t & 63, w = t >> 6, wm = w & 1, wn = w >> 1;
    int l15 = lane & 15, q4 = lane >> 4;
    __shared__ u16 sB2[3][66][136];
    __shared__ float sSc[2][64];
    __shared__ float sEd[16];

    if (t >= 240 && t < 250) {
        int et = t - 240;
        float s = 0.f;
        for (int d = 0; d < 32; ++d) s += etab[et * 32 + d] * econv[d];
        sEd[et] = lk(s);
    }
#pragma unroll
    for (int q = 0; q < 2; ++q) {
        int u = q * 256 + t;
        if (u < 384) {
            int r = u >> 7, rem = u & 127, hcol = rem >> 6, c2 = rem & 63;
            *(u32*)&sB2[r][hcol ? 65 : 0][c2 * 2] = 0u;
        }
    }
#pragma unroll
    for (int it = 0; it < 12; ++it) {
        int u = it * 256 + t;
        int cg = u & 15, j = (u >> 4) & 63, r = u >> 10;
        int ir = i - 1 + r;
        int4 v = make_int4(0, 0, 0, 0);
        if (ir >= 0 && ir < 64)
            v = *(const int4*)(hT + ((b * 64 + ir) * 64 + j) * 128 + cg * 8);
        *(int4*)&sB2[r][j + 1][cg * 8] = v;
    }
    __syncthreads();

    f32x4 acc[4][2];
#pragma unroll
    for (int mt = 0; mt < 4; ++mt)
#pragma unroll
        for (int nt = 0; nt < 2; ++nt) acc[mt][nt] = (f32x4)(0.f);

    for (int kc = 0; kc < 4; ++kc) {
#pragma unroll
        for (int tap = 0; tap < 9; ++tap) {
            int di = tap / 3, dj = tap % 3;
            s16x8 af[4];
#pragma unroll
            for (int mt = 0; mt < 4; ++mt)
                af[mt] = *(const s16x8*)(wA2 + ((((tap * 4 + kc) * 8 + wm * 4 + mt) * 64 + lane) << 3));
#pragma unroll
            for (int nt = 0; nt < 2; ++nt) {
                int jin = wn * 32 + nt * 16 + l15 + dj;
                s16x8 bf = *(const s16x8*)(&sB2[di][jin][kc * 32 + q4 * 8]);
#pragma unroll
                for (int mt = 0; mt < 4; ++mt)
                    acc[mt][nt] = __builtin_amdgcn_mfma_f32_16x16x32_bf16(af[mt], bf, acc[mt][nt], 0, 0, 0);
            }
        }
    }

    float part[2] = {0.f, 0.f};
#pragma unroll
    for (int mt = 0; mt < 4; ++mt) {
        int o0 = wm * 64 + mt * 16 + q4 * 4;
        float4 bb = *(const float4*)(b2 + o0);
        float4 sw = *(const float4*)(score_w + o0);
#pragma unroll
        for (int nt = 0; nt < 2; ++nt) {
            int j = wn * 32 + nt * 16 + l15;
            f32x4 a = acc[mt][nt];
            float v0 = lk(a[0] + bb.x), v1 = lk(a[1] + bb.y);
            float v2 = lk(a[2] + bb.z), v3 = lk(a[3] + bb.w);
            float* dst = m2r + ((b * 128 + o0) * 64 + i) * 64 + j;
            dst[0] = v0; dst[4096] = v1; dst[8192] = v2; dst[12288] = v3;
            part[nt] += sw.x * v0 + sw.y * v1 + sw.z * v2 + sw.w * v3;
        }
    }
#pragma unroll
    for (int nt = 0; nt < 2; ++nt) {
        float p = part[nt];
        p += __shfl_xor(p, 16);
        p += __shfl_xor(p, 32);
        if (q4 == 0) sSc[wm][wn * 32 + nt * 16 + l15] = p;
    }
    __syncthreads();
    if (t < 64) {
        float s = sSc[0][t] + sSc[1][t];
        int gi = (b * 64 + i) * 64 + t;
        float L = lk(Xs[b * 64 + t] + Yo[b * 64 + i]);
        g[gi] = L + sEd[edge_mat[gi]] + m_bias[gi] + lk(s);
    }
}

// ---------------- K5: final softmax+GEMM+residual, block=(b, direction)
__global__ __launch_bounds__(256) void k_gout(const float* __restrict__ g,
                                              const u16* __restrict__ xlT, const u16* __restrict__ ylT,
                                              const float* __restrict__ x, const float* __restrict__ y,
                                              float* __restrict__ out) {
    int b = blockIdx.x >> 1, which = blockIdx.x & 1;
    int t = threadIdx.x;
    int lane = t & 63, w = t >> 6, l15 = lane & 15, q4 = lane >> 4;
    __shared__ float sG[64][68];
    __shared__ u16 Gbf[64][72];
    __shared__ float sRed[128];

#pragma unroll
    for (int r = 0; r < 16; ++r) {
        int idx = r * 256 + t;
        sG[idx >> 6][idx & 63] = g[b * 4096 + idx];
    }
    __syncthreads();

    if (which == 0) {
        if (t < 128) {
            int r = t >> 1, h = t & 1;
            const float4* rp = (const float4*)&sG[r][h * 32];
            float mx = -1e30f;
#pragma unroll
            for (int k = 0; k < 8; ++k) {
                float4 v = rp[k];
                mx = fmaxf(mx, fmaxf(fmaxf(v.x, v.y), fmaxf(v.z, v.w)));
            }
            mx = fmaxf(mx, __shfl_xor(mx, 1));
            float s = 0.f;
#pragma unroll
            for (int k = 0; k < 8; ++k) {
                float4 v = rp[k];
                s += __expf(v.x - mx) + __expf(v.y - mx) + __expf(v.z - mx) + __expf(v.w - mx);
            }
            s += __shfl_xor(s, 1);
            if (h == 0) { sRed[r] = mx; sRed[64 + r] = 1.f / s; }
        }
        __syncthreads();
        // Gbf[m][n] = softmax-row
        int m = t >> 2, q = t & 3;
        float rmax = sRed[m], rinv = sRed[64 + m];
        const float4* rp = (const float4*)&sG[m][q * 16];
#pragma unroll
        for (int g2 = 0; g2 < 2; ++g2) {
            float4 v0 = rp[g2 * 2], v1 = rp[g2 * 2 + 1];
            s16x8 pk;
            pk[0] = (short)f2b(__expf(v0.x - rmax) * rinv);
            pk[1] = (short)f2b(__expf(v0.y - rmax) * rinv);
            pk[2] = (short)f2b(__expf(v0.z - rmax) * rinv);
            pk[3] = (short)f2b(__expf(v0.w - rmax) * rinv);
            pk[4] = (short)f2b(__expf(v1.x - rmax) * rinv);
            pk[5] = (short)f2b(__expf(v1.y - rmax) * rinv);
            pk[6] = (short)f2b(__expf(v1.z - rmax) * rinv);
            pk[7] = (short)f2b(__expf(v1.w - rmax) * rinv);
            *(s16x8*)&Gbf[m][q * 16 + g2 * 8] = pk;
        }
    } else {
        if (t < 128) {
            int n = t >> 1, h = t & 1;
            float mx = -1e30f;
#pragma unroll
            for (int k = 0; k < 32; ++k) mx = fmaxf(mx, sG[h * 32 + k][n]);
            mx = fmaxf(mx, __shfl_xor(mx, 1));
            float s = 0.f;
#pragma unroll
            for (int k = 0; k < 32; ++k) s += __expf(sG[h * 32 + k][n] - mx);
            s += __shfl_xor(s, 1);
            if (h == 0) { sRed[n] = mx; sRed[64 + n] = 1.f / s; }
        }
        __syncthreads();
        // Gbf[n][m] = col-softmax transposed
        int n = t >> 2, q = t & 3;
        float cmax = sRed[n], cinv = sRed[64 + n];
#pragma unroll
        for (int g2 = 0; g2 < 2; ++g2) {
            s16x8 pk;
#pragma unroll
            for (int k = 0; k < 8; ++k) {
                float v = sG[q * 16 + g2 * 8 + k][n];
                pk[k] = (short)f2b(__expf(v - cmax) * cinv);
            }
            *(s16x8*)&Gbf[n][q * 16 + g2 * 8] = pk;
        }
    }
    __syncthreads();

    const u16* lT = which ? xlT : ylT;
    const float* res = which ? y : x;
    int off = which ? 65536 : 0;
    int mcol = w * 16 + l15;
    f32x4 acc[8];
#pragma unroll
    for (int mt = 0; mt < 8; ++mt) acc[mt] = (f32x4)(0.f);
#pragma unroll
    for (int kt = 0; kt < 2; ++kt) {
        s16x8 bfr = *(const s16x8*)&Gbf[mcol][kt * 32 + q4 * 8];
#pragma unroll
        for (int mt = 0; mt < 8; ++mt) {
            s16x8 af = *(const s16x8*)(lT + (b * 128 + mt * 16 + l15) * 64 + kt * 32 + q4 * 8);
            acc[mt] = __builtin_amdgcn_mfma_f32_16x16x32_bf16(af, bfr, acc[mt], 0, 0, 0);
        }
    }
#pragma unroll
    for (int mt = 0; mt < 8; ++mt) {
        int i0 = mt * 16 + q4 * 4;
        f32x4 a = acc[mt];
#pragma unroll
        for (int r = 0; r < 4; ++r) {
            int ad = (b * 128 + i0 + r) * 64 + mcol;
            out[off + ad] = a[r] + res[ad];
        }
    }
}

extern "C" void kernel_launch(void* const* d_in, const int* in_sizes, int n_in,
                              void* d_out, int out_size, void* d_ws, size_t ws_size,
                              hipStream_t stream) {
    const float* x = (const float*)d_in[0];
    const float* y = (const float*)d_in[1];
    const float* m_bias = (const float*)d_in[2];
    const int* edge_mat = (const int*)d_in[3];
    const float* p_bias = (const float*)d_in[4];
    const int* path_mat = (const int*)d_in[5];
    const float* pre = (const float*)d_in[6];
    const float* xc1 = (const float*)d_in[7];
    const float* yc1 = (const float*)d_in[8];
    const float* xc2w = (const float*)d_in[9];
    const float* xc2b = (const float*)d_in[10];
    const float* yc2w = (const float*)d_in[11];
    const float* yc2b = (const float*)d_in[12];
    const float* pconv = (const float*)d_in[13];
    const float* econv = (const float*)d_in[14];
    const float* w1 = (const float*)d_in[15];
    const float* b1 = (const float*)d_in[16];
    const float* w2 = (const float*)d_in[17];
    const float* b2 = (const float*)d_in[18];
    const float* score_w = (const float*)d_in[19];
    const float* xlw = (const float*)d_in[20];
    const float* ylw = (const float*)d_in[21];
    const float* etab = (const float*)d_in[22];
    const float* ptab = (const float*)d_in[23];

    float* Xs = (float*)d_ws;               // 512 f
    float* Yo = Xs + 512;                   // 512 f
    float* g = Yo + 512;                    // 32768 f
    float* xfT = g + 32768;                 // 65536 f
    float* yfT = xfT + 65536;               // 65536 f
    u16* wA1 = (u16*)(yfT + 65536);         // 49152 u16
    u16* wA2 = wA1 + 49152;                 // 147456 u16
    u16* xfb = wA2 + 147456;                // 65536 u16
    u16* yfb = xfb + 65536;
    u16* xlT = yfb + 65536;
    u16* ylT = xlT + 65536;
    u16* menT = ylT + 65536;                // 12582912 u16
    u16* hT = menT + 12582912;              // 4194304 u16

    float* out = (float*)d_out;
    float* out_m2r = out + 131072;

    hipLaunchKernelGGL(k_prep, dim3(1312), dim3(256), 0, stream, w1, w2, wA1, wA2,
                       x, y, xc1, yc1, xc2w, xc2b, yc2w, yc2b, xlw, ylw,
                       xfb, yfb, xfT, yfT, xlT, ylT, Xs, Yo, pre, menT);
    hipLaunchKernelGGL(k_attn, dim3(512), dim3(256), 0, stream, Xs, Yo, xfb, yfb, xfT, yfT,
                       path_mat, p_bias, ptab, pconv, menT);
    hipLaunchKernelGGL(k_conv1, dim3(512), dim3(256), 0, stream, menT, wA1, b1, hT);
    hipLaunchKernelGGL(k_conv2, dim3(512), dim3(256), 0, stream, hT, wA2, b2, score_w,
                       Xs, Yo, etab, econv, edge_mat, m_bias, out_m2r, g);
    hipLaunchKernelGGL(k_gout, dim3(16), dim3(256), 0, stream, g, xlT, ylT, x, y, out);
}

// Round 7
// 190.422 us; speedup vs baseline: 1.1502x; 1.0003x over previous
//
#include <hip/hip_runtime.h>
#include <hip/hip_bf16.h>

// B=8, E=64, CIN=C=PRE=128. fp32 I/O; bf16 MFMA everywhere GEMM-shaped.
// R7: attn+conv1 fused (menT round-trip eliminated); conv2 LDS-free via
// guard-padded hTp[b][66][66][128] zeroed in k_prep.

typedef unsigned short u16;
typedef unsigned int u32;
typedef short s16x8 __attribute__((ext_vector_type(8)));
typedef float f32x4 __attribute__((ext_vector_type(4)));

__device__ __forceinline__ float b2f(u16 u) { return __uint_as_float(((u32)u) << 16); }
__device__ __forceinline__ u16 f2b(float f) {
    u32 x = __float_as_uint(f);
    u32 r = (x + 0x7fffu + ((x >> 16) & 1u)) >> 16;   // RNE
    return (u16)r;
}
__device__ __forceinline__ float lk(float v) { return v >= 0.f ? v : 0.1f * v; }
__device__ __forceinline__ s16x8 cvt8(const float* p) {
    float4 a = ((const float4*)p)[0], c = ((const float4*)p)[1];
    s16x8 r;
    r[0] = (short)f2b(a.x); r[1] = (short)f2b(a.y); r[2] = (short)f2b(a.z); r[3] = (short)f2b(a.w);
    r[4] = (short)f2b(c.x); r[5] = (short)f2b(c.y); r[6] = (short)f2b(c.z); r[7] = (short)f2b(c.w);
    return r;
}

// ---------------- K1: merged prep.
// [0,768): weight frags; [768,800): front GEMMs; [800,1312): pre->preT;
// [1312,1832): hTp guard zeroing.
__global__ __launch_bounds__(256) void k_prep(const float* __restrict__ w1, const float* __restrict__ w2,
                                              u16* __restrict__ wA1, u16* __restrict__ wA2,
                                              const float* __restrict__ x, const float* __restrict__ y,
                                              const float* __restrict__ xc1, const float* __restrict__ yc1,
                                              const float* __restrict__ xc2w, const float* __restrict__ xc2b,
                                              const float* __restrict__ yc2w, const float* __restrict__ yc2b,
                                              const float* __restrict__ xlw, const float* __restrict__ ylw,
                                              u16* __restrict__ xfb, u16* __restrict__ yfb,
                                              float* __restrict__ xfT, float* __restrict__ yfT,
                                              u16* __restrict__ xlT, u16* __restrict__ ylT,
                                              float* __restrict__ Xs, float* __restrict__ Yo,
                                              const float* __restrict__ pre, u16* __restrict__ preT,
                                              u16* __restrict__ hTp) {
    int bid = blockIdx.x;
    int t = threadIdx.x;
    if (bid < 768) {
        int idx = bid * 256 + t;
        if (idx < 49152) {
            int e = idx & 7, lane = (idx >> 3) & 63, mtg = (idx >> 9) & 7, kc = idx >> 12;
            int o = mtg * 16 + (lane & 15), c = kc * 32 + ((lane >> 4) << 3) + e;
            wA1[idx] = f2b(w1[o * 384 + c]);
        } else {
            int id2 = idx - 49152;
            if (id2 < 147456) {
                int e = id2 & 7, lane = (id2 >> 3) & 63, mtg = (id2 >> 9) & 7;
                int kc = (id2 >> 12) & 3, tap = id2 >> 14;
                int o = mtg * 16 + (lane & 15), c = kc * 32 + ((lane >> 4) << 3) + e;
                wA2[id2] = f2b(w2[(o * 128 + c) * 9 + tap]);
            }
        }
        return;
    }
    if (bid < 800) {
        int r = bid - 768;
        int b = r >> 2, g4 = r & 3;
        int lane = t & 63, w = t >> 6, l15 = lane & 15, q4 = lane >> 4;
        __shared__ u16 sT[64][136];
        const float* src = (g4 == 0 || g4 == 2) ? x : y;
        const float* wptr = (g4 == 0) ? xc1 : (g4 == 1) ? yc1 : (g4 == 2) ? xlw : ylw;
        {
            int i = t >> 1, m0 = (t & 1) * 32;
            const float4* ps = (const float4*)(src + (b * 128 + i) * 64 + m0);
#pragma unroll
            for (int q = 0; q < 8; ++q) {
                float4 v = ps[q];
                int m = m0 + q * 4;
                sT[m + 0][i] = f2b(v.x); sT[m + 1][i] = f2b(v.y);
                sT[m + 2][i] = f2b(v.z); sT[m + 3][i] = f2b(v.w);
            }
        }
        __syncthreads();
        int m = w * 16 + l15;
        f32x4 acc[8];
#pragma unroll
        for (int mt = 0; mt < 8; ++mt) acc[mt] = (f32x4)(0.f);
#pragma unroll
        for (int kt = 0; kt < 4; ++kt) {
            s16x8 bfr = *(const s16x8*)&sT[m][kt * 32 + q4 * 8];
#pragma unroll
            for (int mt = 0; mt < 8; ++mt) {
                s16x8 af = cvt8(wptr + (mt * 16 + l15) * 128 + kt * 32 + q4 * 8);
                acc[mt] = __builtin_amdgcn_mfma_f32_16x16x32_bf16(af, bfr, acc[mt], 0, 0, 0);
            }
        }
        if (g4 == 0 || g4 == 1) {
            u16* fb = (g4 == 0) ? xfb : yfb;
            float* fT = (g4 == 0) ? xfT : yfT;
            const float* c2w = (g4 == 0) ? xc2w : yc2w;
            const float* c2b = (g4 == 0) ? xc2b : yc2b;
            float* dvec = (g4 == 0) ? Xs : Yo;
            float sp = 0.f;
#pragma unroll
            for (int mt = 0; mt < 8; ++mt) {
                int c0 = mt * 16 + q4 * 4;
                f32x4 a = acc[mt];
                fb[(b * 128 + c0 + 0) * 64 + m] = f2b(a[0]);
                fb[(b * 128 + c0 + 1) * 64 + m] = f2b(a[1]);
                fb[(b * 128 + c0 + 2) * 64 + m] = f2b(a[2]);
                fb[(b * 128 + c0 + 3) * 64 + m] = f2b(a[3]);
                *(float4*)(fT + (b * 64 + m) * 128 + c0) = make_float4(a[0], a[1], a[2], a[3]);
                float4 wv = *(const float4*)(c2w + c0);
                sp += wv.x * a[0] + wv.y * a[1] + wv.z * a[2] + wv.w * a[3];
            }
            sp += __shfl_xor(sp, 16);
            sp += __shfl_xor(sp, 32);
            if (q4 == 0) dvec[b * 64 + m] = sp + c2b[0];
        } else {
            u16* lT = (g4 == 2) ? xlT : ylT;
#pragma unroll
            for (int mt = 0; mt < 8; ++mt) {
                int i0 = mt * 16 + q4 * 4;
                f32x4 a = acc[mt];
                lT[(b * 128 + i0 + 0) * 64 + m] = f2b(a[0]);
                lT[(b * 128 + i0 + 1) * 64 + m] = f2b(a[1]);
                lT[(b * 128 + i0 + 2) * 64 + m] = f2b(a[2]);
                lT[(b * 128 + i0 + 3) * 64 + m] = f2b(a[3]);
            }
        }
        return;
    }
    if (bid < 1312) {
        int r = bid - 800;
        int b = r >> 6, i = r & 63;
        int j = t & 63, pg = t >> 6;
#pragma unroll
        for (int oc = 0; oc < 4; ++oc) {
            int p0 = pg * 32 + oc * 8;
            s16x8 v;
#pragma unroll
            for (int k = 0; k < 8; ++k)
                v[k] = (short)f2b(pre[((b * 128 + p0 + k) * 64 + i) * 64 + j]);
            *(s16x8*)(preT + ((b * 64 + i) * 64 + j) * 128 + p0) = v;
        }
        return;
    }
    {
        // hTp guard zeroing: 520 blocks x 256 threads x 1 u32 = 133120 u32
        int gid = (bid - 1312) * 256 + t;
        int b = gid / 16640;
        int r = gid - b * 16640;
        u32 idx;
        if (r < 8448) {
            int row = r / 4224, rem = r - row * 4224;
            int jj = rem >> 6, o2 = rem & 63;
            idx = (u32)(((b * 66 + (row ? 65 : 0)) * 66 + jj) * 64 + o2);
        } else {
            int r2 = r - 8448;
            int ii = r2 >> 7, rem = r2 & 127;
            int side = rem >> 6, o2 = rem & 63;
            idx = (u32)(((b * 66 + ii + 1) * 66 + (side ? 65 : 0)) * 64 + o2);
        }
        ((u32*)hTp)[idx] = 0u;
    }
}

// ---------------- K2: fused attention + conv1. Block (b, e=i). Writes hTp interior row.
__global__ __launch_bounds__(256) void k_attnc(const float* __restrict__ Xs, const float* __restrict__ Yo,
                                               const u16* __restrict__ xfb, const u16* __restrict__ yfb,
                                               const float* __restrict__ xfT, const float* __restrict__ yfT,
                                               const int* __restrict__ path_mat, const float* __restrict__ p_bias,
                                               const float* __restrict__ ptab, const float* __restrict__ pconv,
                                               const u16* __restrict__ preT, const u16* __restrict__ wA1,
                                               const float* __restrict__ b1, u16* __restrict__ hTp) {
    int b = blockIdx.x >> 6, e = blockIdx.x & 63;
    int t = threadIdx.x;
    int lane = t & 63, w = t >> 6;
    __shared__ __align__(16) char smem0[64 * 264 * 2];   // sA (f32 [64][68]) aliased with sMen (u16 [64][264])
    float* sAf = (float*)smem0;
    u16* sMen = (u16*)smem0;
    __shared__ u16 Abf[64][72];
    __shared__ u16 E2bf[64][72];
    __shared__ float sRed[256];
    __shared__ float sPdot[20];
    __shared__ float sXv[64], sYv[64];

    if (t < 20) {
        float s = 0.f;
        for (int d = 0; d < 32; ++d) s += ptab[t * 32 + d] * pconv[d];
        sPdot[t] = lk(s);
    } else if (t >= 64 && t < 128) {
        sXv[t - 64] = Xs[b * 64 + t - 64];
    } else if (t >= 128 && t < 192) {
        sYv[t - 128] = Yo[b * 64 + t - 128];
    }
    __syncthreads();

    // P1: local scores
    {
        int m = t >> 2, n0 = (t & 3) * 16;
        int base = (((b * 64 + e) * 64 + m) * 64 + n0);
        const int4* pm4 = (const int4*)(path_mat + base);
        const float4* pb4 = (const float4*)(p_bias + base);
        float yom = sYv[m];
#pragma unroll
        for (int q = 0; q < 4; ++q) {
            int4 pm = pm4[q]; float4 pb = pb4[q];
            int n = n0 + q * 4;
            float4 v;
            v.x = lk(sXv[n + 0] + yom) + sPdot[pm.x] + pb.x;
            v.y = lk(sXv[n + 1] + yom) + sPdot[pm.y] + pb.y;
            v.z = lk(sXv[n + 2] + yom) + sPdot[pm.z] + pb.z;
            v.w = lk(sXv[n + 3] + yom) + sPdot[pm.w] + pb.w;
            *(float4*)&sAf[m * 68 + n] = v;
        }
    }
    __syncthreads();

    // P2: row/col stats
    if (t < 128) {
        int r = t >> 1, h = t & 1;
        const float4* rp = (const float4*)&sAf[r * 68 + h * 32];
        float mx = -1e30f;
#pragma unroll
        for (int k = 0; k < 8; ++k) {
            float4 v = rp[k];
            mx = fmaxf(mx, fmaxf(fmaxf(v.x, v.y), fmaxf(v.z, v.w)));
        }
        mx = fmaxf(mx, __shfl_xor(mx, 1));
        float s = 0.f;
#pragma unroll
        for (int k = 0; k < 8; ++k) {
            float4 v = rp[k];
            s += __expf(v.x - mx) + __expf(v.y - mx) + __expf(v.z - mx) + __expf(v.w - mx);
        }
        s += __shfl_xor(s, 1);
        if (h == 0) { sRed[r] = mx; sRed[64 + r] = 1.f / s; }
    } else {
        int n = (t - 128) >> 1, h = t & 1;
        float mx = -1e30f;
#pragma unroll
        for (int k = 0; k < 32; ++k) mx = fmaxf(mx, sAf[(h * 32 + k) * 68 + n]);
        mx = fmaxf(mx, __shfl_xor(mx, 1));
        float s = 0.f;
#pragma unroll
        for (int k = 0; k < 32; ++k) s += __expf(sAf[(h * 32 + k) * 68 + n] - mx);
        s += __shfl_xor(s, 1);
        if (h == 0) { sRed[128 + n] = mx; sRed[192 + n] = 1.f / s; }
    }
    __syncthreads();

    // P3: softmax fragments
    {
        int m = t >> 2, q = t & 3;
        float rmax = sRed[m], rinv = sRed[64 + m];
        const float4* rp = (const float4*)&sAf[m * 68 + q * 16];
#pragma unroll
        for (int g2 = 0; g2 < 2; ++g2) {
            float4 v0 = rp[g2 * 2], v1 = rp[g2 * 2 + 1];
            s16x8 pk;
            pk[0] = (short)f2b(__expf(v0.x - rmax) * rinv);
            pk[1] = (short)f2b(__expf(v0.y - rmax) * rinv);
            pk[2] = (short)f2b(__expf(v0.z - rmax) * rinv);
            pk[3] = (short)f2b(__expf(v0.w - rmax) * rinv);
            pk[4] = (short)f2b(__expf(v1.x - rmax) * rinv);
            pk[5] = (short)f2b(__expf(v1.y - rmax) * rinv);
            pk[6] = (short)f2b(__expf(v1.z - rmax) * rinv);
            pk[7] = (short)f2b(__expf(v1.w - rmax) * rinv);
            *(s16x8*)&Abf[m][q * 16 + g2 * 8] = pk;
        }
    }
    {
        int n = t >> 2, q = t & 3;
        float cmax = sRed[128 + n], cinv = sRed[192 + n];
#pragma unroll
        for (int g2 = 0; g2 < 2; ++g2) {
            s16x8 pk;
#pragma unroll
            for (int k = 0; k < 8; ++k) {
                float v = sAf[(q * 16 + g2 * 8 + k) * 68 + n];
                pk[k] = (short)f2b(__expf(v - cmax) * cinv);
            }
            *(s16x8*)&E2bf[n][q * 16 + g2 * 8] = pk;
        }
    }
    __syncthreads();   // sAf dead; sMen may be written now

    int l15 = lane & 15, q4 = lane >> 4;
    // GEMM1: xret[c][m] -> sMen[m][c], c<128
    {
        f32x4 acc[2][4];
#pragma unroll
        for (int ci = 0; ci < 2; ++ci)
#pragma unroll
            for (int mt = 0; mt < 4; ++mt) acc[ci][mt] = (f32x4)(0.f);
#pragma unroll
        for (int kt = 0; kt < 2; ++kt) {
            s16x8 afr[2];
#pragma unroll
            for (int ci = 0; ci < 2; ++ci) {
                int c = (2 * w + ci) * 16 + l15;
                afr[ci] = *(const s16x8*)(yfb + (b * 128 + c) * 64 + kt * 32 + q4 * 8);
            }
            s16x8 bfr[4];
#pragma unroll
            for (int mt = 0; mt < 4; ++mt)
                bfr[mt] = *(const s16x8*)&Abf[mt * 16 + l15][kt * 32 + q4 * 8];
#pragma unroll
            for (int ci = 0; ci < 2; ++ci)
#pragma unroll
                for (int mt = 0; mt < 4; ++mt)
                    acc[ci][mt] = __builtin_amdgcn_mfma_f32_16x16x32_bf16(afr[ci], bfr[mt], acc[ci][mt], 0, 0, 0);
        }
#pragma unroll
        for (int ci = 0; ci < 2; ++ci) {
            int c0 = (2 * w + ci) * 16 + q4 * 4;
#pragma unroll
            for (int mt = 0; mt < 4; ++mt) {
                int m = mt * 16 + l15;
                float4 res = *(const float4*)(xfT + (b * 64 + m) * 128 + c0);
                f32x4 a = acc[ci][mt];
                u32 lo = (u32)f2b(lk(a[0] + res.x)) | ((u32)f2b(lk(a[1] + res.y)) << 16);
                u32 hi = (u32)f2b(lk(a[2] + res.z)) | ((u32)f2b(lk(a[3] + res.w)) << 16);
                *(uint2*)&sMen[m * 264 + c0] = make_uint2(lo, hi);
            }
        }
    }
    // GEMM2: yret[c][n] -> sMen[n][128+c]
    {
        f32x4 acc[2][4];
#pragma unroll
        for (int ci = 0; ci < 2; ++ci)
#pragma unroll
            for (int nt = 0; nt < 4; ++nt) acc[ci][nt] = (f32x4)(0.f);
#pragma unroll
        for (int kt = 0; kt < 2; ++kt) {
            s16x8 afr[2];
#pragma unroll
            for (int ci = 0; ci < 2; ++ci) {
                int c = (2 * w + ci) * 16 + l15;
                afr[ci] = *(const s16x8*)(xfb + (b * 128 + c) * 64 + kt * 32 + q4 * 8);
            }
            s16x8 bfr[4];
#pragma unroll
            for (int nt = 0; nt < 4; ++nt)
                bfr[nt] = *(const s16x8*)&E2bf[nt * 16 + l15][kt * 32 + q4 * 8];
#pragma unroll
            for (int ci = 0; ci < 2; ++ci)
#pragma unroll
                for (int nt = 0; nt < 4; ++nt)
                    acc[ci][nt] = __builtin_amdgcn_mfma_f32_16x16x32_bf16(afr[ci], bfr[nt], acc[ci][nt], 0, 0, 0);
        }
#pragma unroll
        for (int ci = 0; ci < 2; ++ci) {
            int c0 = (2 * w + ci) * 16 + q4 * 4;
#pragma unroll
            for (int nt = 0; nt < 4; ++nt) {
                int n = nt * 16 + l15;
                float4 res = *(const float4*)(yfT + (b * 64 + n) * 128 + c0);
                f32x4 a = acc[ci][nt];
                u32 lo = (u32)f2b(lk(a[0] + res.x)) | ((u32)f2b(lk(a[1] + res.y)) << 16);
                u32 hi = (u32)f2b(lk(a[2] + res.z)) | ((u32)f2b(lk(a[3] + res.w)) << 16);
                *(uint2*)&sMen[n * 264 + 128 + c0] = make_uint2(lo, hi);
            }
        }
    }
    __syncthreads();

    // conv1 for output row i=e: B from sMen (kc<8) / preT (kc>=8)
    {
        int wm = w & 1, wn = w >> 1;
        f32x4 acc[4][2];
#pragma unroll
        for (int mt = 0; mt < 4; ++mt)
#pragma unroll
            for (int nt = 0; nt < 2; ++nt) acc[mt][nt] = (f32x4)(0.f);
        const u16* prow = preT + (b * 64 + e) * 64 * 128;
        for (int kc = 0; kc < 12; ++kc) {
            s16x8 af[4];
#pragma unroll
            for (int mt = 0; mt < 4; ++mt)
                af[mt] = *(const s16x8*)(wA1 + (((kc * 8 + wm * 4 + mt) * 64 + lane) << 3));
            s16x8 bf[2];
#pragma unroll
            for (int nt = 0; nt < 2; ++nt) {
                int j = (wn * 2 + nt) * 16 + l15;
                bf[nt] = (kc < 8) ? *(const s16x8*)&sMen[j * 264 + kc * 32 + q4 * 8]
                                  : *(const s16x8*)(prow + j * 128 + (kc - 8) * 32 + q4 * 8);
            }
#pragma unroll
            for (int mt = 0; mt < 4; ++mt)
#pragma unroll
                for (int nt = 0; nt < 2; ++nt)
                    acc[mt][nt] = __builtin_amdgcn_mfma_f32_16x16x32_bf16(af[mt], bf[nt], acc[mt][nt], 0, 0, 0);
        }
#pragma unroll
        for (int mt = 0; mt < 4; ++mt) {
            int o0 = (wm * 4 + mt) * 16 + q4 * 4;
            float4 bb = *(const float4*)(b1 + o0);
#pragma unroll
            for (int nt = 0; nt < 2; ++nt) {
                int j = (wn * 2 + nt) * 16 + l15;
                f32x4 a = acc[mt][nt];
                u32 lo = (u32)f2b(lk(a[0] + bb.x)) | ((u32)f2b(lk(a[1] + bb.y)) << 16);
                u32 hi = (u32)f2b(lk(a[2] + bb.z)) | ((u32)f2b(lk(a[3] + bb.w)) << 16);
                *(uint2*)(hTp + ((b * 66 + e + 1) * 66 + j + 1) * 128 + o0) = make_uint2(lo, hi);
            }
        }
    }
}

// ---------------- K3: conv2 (3x3 SAME) MFMA, LDS-free B via padded hTp; fused scores+gbase
__global__ __launch_bounds__(256) void k_conv2(const u16* __restrict__ hTp, const u16* __restrict__ wA2,
                                               const float* __restrict__ b2, const float* __restrict__ score_w,
                                               const float* __restrict__ Xs, const float* __restrict__ Yo,
                                               const float* __restrict__ etab, const float* __restrict__ econv,
                                               const int* __restrict__ edge_mat, const float* __restrict__ m_bias,
                                               float* __restrict__ m2r, float* __restrict__ g) {
    int b = blockIdx.x >> 6, i = blockIdx.x & 63;
    int t = threadIdx.x;
    int lane = t & 63, w = t >> 6, wm = w & 1, wn = w >> 1;
    int l15 = lane & 15, q4 = lane >> 4;
    __shared__ float sSc[2][64];
    __shared__ float sEd[16];

    if (t >= 240 && t < 250) {
        int et = t - 240;
        float s = 0.f;
        for (int d = 0; d < 32; ++d) s += etab[et * 32 + d] * econv[d];
        sEd[et] = lk(s);
    }

    f32x4 acc[4][2];
#pragma unroll
    for (int mt = 0; mt < 4; ++mt)
#pragma unroll
        for (int nt = 0; nt < 2; ++nt) acc[mt][nt] = (f32x4)(0.f);

    for (int kc = 0; kc < 4; ++kc) {
#pragma unroll
        for (int tap = 0; tap < 9; ++tap) {
            int di = tap / 3, dj = tap % 3;
            s16x8 af[4];
#pragma unroll
            for (int mt = 0; mt < 4; ++mt)
                af[mt] = *(const s16x8*)(wA2 + ((((tap * 4 + kc) * 8 + wm * 4 + mt) * 64 + lane) << 3));
#pragma unroll
            for (int nt = 0; nt < 2; ++nt) {
                int j = wn * 32 + nt * 16 + l15;
                s16x8 bf = *(const s16x8*)(hTp + ((b * 66 + i + di) * 66 + j + dj) * 128 + kc * 32 + q4 * 8);
#pragma unroll
                for (int mt = 0; mt < 4; ++mt)
                    acc[mt][nt] = __builtin_amdgcn_mfma_f32_16x16x32_bf16(af[mt], bf, acc[mt][nt], 0, 0, 0);
            }
        }
    }

    float part[2] = {0.f, 0.f};
#pragma unroll
    for (int mt = 0; mt < 4; ++mt) {
        int o0 = wm * 64 + mt * 16 + q4 * 4;
        float4 bb = *(const float4*)(b2 + o0);
        float4 sw = *(const float4*)(score_w + o0);
#pragma unroll
        for (int nt = 0; nt < 2; ++nt) {
            int j = wn * 32 + nt * 16 + l15;
            f32x4 a = acc[mt][nt];
            float v0 = lk(a[0] + bb.x), v1 = lk(a[1] + bb.y);
            float v2 = lk(a[2] + bb.z), v3 = lk(a[3] + bb.w);
            float* dst = m2r + ((b * 128 + o0) * 64 + i) * 64 + j;
            dst[0] = v0; dst[4096] = v1; dst[8192] = v2; dst[12288] = v3;
            part[nt] += sw.x * v0 + sw.y * v1 + sw.z * v2 + sw.w * v3;
        }
    }
#pragma unroll
    for (int nt = 0; nt < 2; ++nt) {
        float p = part[nt];
        p += __shfl_xor(p, 16);
        p += __shfl_xor(p, 32);
        if (q4 == 0) sSc[wm][wn * 32 + nt * 16 + l15] = p;
    }
    __syncthreads();
    if (t < 64) {
        float s = sSc[0][t] + sSc[1][t];
        int gi = (b * 64 + i) * 64 + t;
        float L = lk(Xs[b * 64 + t] + Yo[b * 64 + i]);
        g[gi] = L + sEd[edge_mat[gi]] + m_bias[gi] + lk(s);
    }
}

// ---------------- K4: final softmax+GEMM+residual, block=(b, direction)
__global__ __launch_bounds__(256) void k_gout(const float* __restrict__ g,
                                              const u16* __restrict__ xlT, const u16* __restrict__ ylT,
                                              const float* __restrict__ x, const float* __restrict__ y,
                                              float* __restrict__ out) {
    int b = blockIdx.x >> 1, which = blockIdx.x & 1;
    int t = threadIdx.x;
    int lane = t & 63, w = t >> 6, l15 = lane & 15, q4 = lane >> 4;
    __shared__ float sG[64][68];
    __shared__ u16 Gbf[64][72];
    __shared__ float sRed[128];

#pragma unroll
    for (int r = 0; r < 16; ++r) {
        int idx = r * 256 + t;
        sG[idx >> 6][idx & 63] = g[b * 4096 + idx];
    }
    __syncthreads();

    if (which == 0) {
        if (t < 128) {
            int r = t >> 1, h = t & 1;
            const float4* rp = (const float4*)&sG[r][h * 32];
            float mx = -1e30f;
#pragma unroll
            for (int k = 0; k < 8; ++k) {
                float4 v = rp[k];
                mx = fmaxf(mx, fmaxf(fmaxf(v.x, v.y), fmaxf(v.z, v.w)));
            }
            mx = fmaxf(mx, __shfl_xor(mx, 1));
            float s = 0.f;
#pragma unroll
            for (int k = 0; k < 8; ++k) {
                float4 v = rp[k];
                s += __expf(v.x - mx) + __expf(v.y - mx) + __expf(v.z - mx) + __expf(v.w - mx);
            }
            s += __shfl_xor(s, 1);
            if (h == 0) { sRed[r] = mx; sRed[64 + r] = 1.f / s; }
        }
        __syncthreads();
        int m = t >> 2, q = t & 3;
        float rmax = sRed[m], rinv = sRed[64 + m];
        const float4* rp = (const float4*)&sG[m][q * 16];
#pragma unroll
        for (int g2 = 0; g2 < 2; ++g2) {
            float4 v0 = rp[g2 * 2], v1 = rp[g2 * 2 + 1];
            s16x8 pk;
            pk[0] = (short)f2b(__expf(v0.x - rmax) * rinv);
            pk[1] = (short)f2b(__expf(v0.y - rmax) * rinv);
            pk[2] = (short)f2b(__expf(v0.z - rmax) * rinv);
            pk[3] = (short)f2b(__expf(v0.w - rmax) * rinv);
            pk[4] = (short)f2b(__expf(v1.x - rmax) * rinv);
            pk[5] = (short)f2b(__expf(v1.y - rmax) * rinv);
            pk[6] = (short)f2b(__expf(v1.z - rmax) * rinv);
            pk[7] = (short)f2b(__expf(v1.w - rmax) * rinv);
            *(s16x8*)&Gbf[m][q * 16 + g2 * 8] = pk;
        }
    } else {
        if (t < 128) {
            int n = t >> 1, h = t & 1;
            float mx = -1e30f;
#pragma unroll
            for (int k = 0; k < 32; ++k) mx = fmaxf(mx, sG[h * 32 + k][n]);
            mx = fmaxf(mx, __shfl_xor(mx, 1));
            float s = 0.f;
#pragma unroll
            for (int k = 0; k < 32; ++k) s += __expf(sG[h * 32 + k][n] - mx);
            s += __shfl_xor(s, 1);
            if (h == 0) { sRed[n] = mx; sRed[64 + n] = 1.f / s; }
        }
        __syncthreads();
        int n = t >> 2, q = t & 3;
        float cmax = sRed[n], cinv = sRed[64 + n];
#pragma unroll
        for (int g2 = 0; g2 < 2; ++g2) {
            s16x8 pk;
#pragma unroll
            for (int k = 0; k < 8; ++k) {
                float v = sG[q * 16 + g2 * 8 + k][n];
                pk[k] = (short)f2b(__expf(v - cmax) * cinv);
            }
            *(s16x8*)&Gbf[n][q * 16 + g2 * 8] = pk;
        }
    }
    __syncthreads();

    const u16* lT = which ? xlT : ylT;
    const float* res = which ? y : x;
    int off = which ? 65536 : 0;
    int mcol = w * 16 + l15;
    f32x4 acc[8];
#pragma unroll
    for (int mt = 0; mt < 8; ++mt) acc[mt] = (f32x4)(0.f);
#pragma unroll
    for (int kt = 0; kt < 2; ++kt) {
        s16x8 bfr = *(const s16x8*)&Gbf[mcol][kt * 32 + q4 * 8];
#pragma unroll
        for (int mt = 0; mt < 8; ++mt) {
            s16x8 af = *(const s16x8*)(lT + (b * 128 + mt * 16 + l15) * 64 + kt * 32 + q4 * 8);
            acc[mt] = __builtin_amdgcn_mfma_f32_16x16x32_bf16(af, bfr, acc[mt], 0, 0, 0);
        }
    }
#pragma unroll
    for (int mt = 0; mt < 8; ++mt) {
        int i0 = mt * 16 + q4 * 4;
        f32x4 a = acc[mt];
#pragma unroll
        for (int r = 0; r < 4; ++r) {
            int ad = (b * 128 + i0 + r) * 64 + mcol;
            out[off + ad] = a[r] + res[ad];
        }
    }
}

extern "C" void kernel_launch(void* const* d_in, const int* in_sizes, int n_in,
                              void* d_out, int out_size, void* d_ws, size_t ws_size,
                              hipStream_t stream) {
    const float* x = (const float*)d_in[0];
    const float* y = (const float*)d_in[1];
    const float* m_bias = (const float*)d_in[2];
    const int* edge_mat = (const int*)d_in[3];
    const float* p_bias = (const float*)d_in[4];
    const int* path_mat = (const int*)d_in[5];
    const float* pre = (const float*)d_in[6];
    const float* xc1 = (const float*)d_in[7];
    const float* yc1 = (const float*)d_in[8];
    const float* xc2w = (const float*)d_in[9];
    const float* xc2b = (const float*)d_in[10];
    const float* yc2w = (const float*)d_in[11];
    const float* yc2b = (const float*)d_in[12];
    const float* pconv = (const float*)d_in[13];
    const float* econv = (const float*)d_in[14];
    const float* w1 = (const float*)d_in[15];
    const float* b1 = (const float*)d_in[16];
    const float* w2 = (const float*)d_in[17];
    const float* b2 = (const float*)d_in[18];
    const float* score_w = (const float*)d_in[19];
    const float* xlw = (const float*)d_in[20];
    const float* ylw = (const float*)d_in[21];
    const float* etab = (const float*)d_in[22];
    const float* ptab = (const float*)d_in[23];

    float* Xs = (float*)d_ws;               // 512 f
    float* Yo = Xs + 512;                   // 512 f
    float* g = Yo + 512;                    // 32768 f
    float* xfT = g + 32768;                 // 65536 f
    float* yfT = xfT + 65536;               // 65536 f
    u16* wA1 = (u16*)(yfT + 65536);         // 49152 u16
    u16* wA2 = wA1 + 49152;                 // 147456 u16
    u16* xfb = wA2 + 147456;                // 65536 u16
    u16* yfb = xfb + 65536;
    u16* xlT = yfb + 65536;
    u16* ylT = xlT + 65536;
    u16* preT = ylT + 65536;                // 4194304 u16 (8 MiB)
    u16* hTp = preT + 4194304;              // 4460544 u16 (8.9 MiB)

    float* out = (float*)d_out;
    float* out_m2r = out + 131072;

    hipLaunchKernelGGL(k_prep, dim3(1832), dim3(256), 0, stream, w1, w2, wA1, wA2,
                       x, y, xc1, yc1, xc2w, xc2b, yc2w, yc2b, xlw, ylw,
                       xfb, yfb, xfT, yfT, xlT, ylT, Xs, Yo, pre, preT, hTp);
    hipLaunchKernelGGL(k_attnc, dim3(512), dim3(256), 0, stream, Xs, Yo, xfb, yfb, xfT, yfT,
                       path_mat, p_bias, ptab, pconv, preT, wA1, b1, hTp);
    hipLaunchKernelGGL(k_conv2, dim3(512), dim3(256), 0, stream, hTp, wA2, b2, score_w,
                       Xs, Yo, etab, econv, edge_mat, m_bias, out_m2r, g);
    hipLaunchKernelGGL(k_gout, dim3(16), dim3(256), 0, stream, g, xlT, ylT, x, y, out);
}

// Round 8
// 179.640 us; speedup vs baseline: 1.2193x; 1.0600x over previous
//
#include <hip/hip_runtime.h>
#include <hip/hip_bf16.h>

// B=8, E=64, CIN=C=PRE=128. fp32 I/O; bf16 MFMA everywhere GEMM-shaped.
// R8: exp-once softmax (max-shift identity) in attnc+gout; conv2 back to
// LDS-staged halo (R6-proven) with R7's fused conv1 + inline gbase kept.

typedef unsigned short u16;
typedef unsigned int u32;
typedef short s16x8 __attribute__((ext_vector_type(8)));
typedef float f32x4 __attribute__((ext_vector_type(4)));

__device__ __forceinline__ float b2f(u16 u) { return __uint_as_float(((u32)u) << 16); }
__device__ __forceinline__ u16 f2b(float f) {
    u32 x = __float_as_uint(f);
    u32 r = (x + 0x7fffu + ((x >> 16) & 1u)) >> 16;   // RNE
    return (u16)r;
}
__device__ __forceinline__ float lk(float v) { return v >= 0.f ? v : 0.1f * v; }
__device__ __forceinline__ s16x8 cvt8(const float* p) {
    float4 a = ((const float4*)p)[0], c = ((const float4*)p)[1];
    s16x8 r;
    r[0] = (short)f2b(a.x); r[1] = (short)f2b(a.y); r[2] = (short)f2b(a.z); r[3] = (short)f2b(a.w);
    r[4] = (short)f2b(c.x); r[5] = (short)f2b(c.y); r[6] = (short)f2b(c.z); r[7] = (short)f2b(c.w);
    return r;
}

// ---------------- K1: merged prep.
// [0,768): weight frags; [768,800): front GEMMs; [800,1312): pre->preT.
__global__ __launch_bounds__(256) void k_prep(const float* __restrict__ w1, const float* __restrict__ w2,
                                              u16* __restrict__ wA1, u16* __restrict__ wA2,
                                              const float* __restrict__ x, const float* __restrict__ y,
                                              const float* __restrict__ xc1, const float* __restrict__ yc1,
                                              const float* __restrict__ xc2w, const float* __restrict__ xc2b,
                                              const float* __restrict__ yc2w, const float* __restrict__ yc2b,
                                              const float* __restrict__ xlw, const float* __restrict__ ylw,
                                              u16* __restrict__ xfb, u16* __restrict__ yfb,
                                              float* __restrict__ xfT, float* __restrict__ yfT,
                                              u16* __restrict__ xlT, u16* __restrict__ ylT,
                                              float* __restrict__ Xs, float* __restrict__ Yo,
                                              const float* __restrict__ pre, u16* __restrict__ preT) {
    int bid = blockIdx.x;
    int t = threadIdx.x;
    if (bid < 768) {
        int idx = bid * 256 + t;
        if (idx < 49152) {
            int e = idx & 7, lane = (idx >> 3) & 63, mtg = (idx >> 9) & 7, kc = idx >> 12;
            int o = mtg * 16 + (lane & 15), c = kc * 32 + ((lane >> 4) << 3) + e;
            wA1[idx] = f2b(w1[o * 384 + c]);
        } else {
            int id2 = idx - 49152;
            if (id2 < 147456) {
                int e = id2 & 7, lane = (id2 >> 3) & 63, mtg = (id2 >> 9) & 7;
                int kc = (id2 >> 12) & 3, tap = id2 >> 14;
                int o = mtg * 16 + (lane & 15), c = kc * 32 + ((lane >> 4) << 3) + e;
                wA2[id2] = f2b(w2[(o * 128 + c) * 9 + tap]);
            }
        }
        return;
    }
    if (bid < 800) {
        int r = bid - 768;
        int b = r >> 2, g4 = r & 3;
        int lane = t & 63, w = t >> 6, l15 = lane & 15, q4 = lane >> 4;
        __shared__ u16 sT[64][136];
        const float* src = (g4 == 0 || g4 == 2) ? x : y;
        const float* wptr = (g4 == 0) ? xc1 : (g4 == 1) ? yc1 : (g4 == 2) ? xlw : ylw;
        {
            int i = t >> 1, m0 = (t & 1) * 32;
            const float4* ps = (const float4*)(src + (b * 128 + i) * 64 + m0);
#pragma unroll
            for (int q = 0; q < 8; ++q) {
                float4 v = ps[q];
                int m = m0 + q * 4;
                sT[m + 0][i] = f2b(v.x); sT[m + 1][i] = f2b(v.y);
                sT[m + 2][i] = f2b(v.z); sT[m + 3][i] = f2b(v.w);
            }
        }
        __syncthreads();
        int m = w * 16 + l15;
        f32x4 acc[8];
#pragma unroll
        for (int mt = 0; mt < 8; ++mt) acc[mt] = (f32x4)(0.f);
#pragma unroll
        for (int kt = 0; kt < 4; ++kt) {
            s16x8 bfr = *(const s16x8*)&sT[m][kt * 32 + q4 * 8];
#pragma unroll
            for (int mt = 0; mt < 8; ++mt) {
                s16x8 af = cvt8(wptr + (mt * 16 + l15) * 128 + kt * 32 + q4 * 8);
                acc[mt] = __builtin_amdgcn_mfma_f32_16x16x32_bf16(af, bfr, acc[mt], 0, 0, 0);
            }
        }
        if (g4 == 0 || g4 == 1) {
            u16* fb = (g4 == 0) ? xfb : yfb;
            float* fT = (g4 == 0) ? xfT : yfT;
            const float* c2w = (g4 == 0) ? xc2w : yc2w;
            const float* c2b = (g4 == 0) ? xc2b : yc2b;
            float* dvec = (g4 == 0) ? Xs : Yo;
            float sp = 0.f;
#pragma unroll
            for (int mt = 0; mt < 8; ++mt) {
                int c0 = mt * 16 + q4 * 4;
                f32x4 a = acc[mt];
                fb[(b * 128 + c0 + 0) * 64 + m] = f2b(a[0]);
                fb[(b * 128 + c0 + 1) * 64 + m] = f2b(a[1]);
                fb[(b * 128 + c0 + 2) * 64 + m] = f2b(a[2]);
                fb[(b * 128 + c0 + 3) * 64 + m] = f2b(a[3]);
                *(float4*)(fT + (b * 64 + m) * 128 + c0) = make_float4(a[0], a[1], a[2], a[3]);
                float4 wv = *(const float4*)(c2w + c0);
                sp += wv.x * a[0] + wv.y * a[1] + wv.z * a[2] + wv.w * a[3];
            }
            sp += __shfl_xor(sp, 16);
            sp += __shfl_xor(sp, 32);
            if (q4 == 0) dvec[b * 64 + m] = sp + c2b[0];
        } else {
            u16* lT = (g4 == 2) ? xlT : ylT;
#pragma unroll
            for (int mt = 0; mt < 8; ++mt) {
                int i0 = mt * 16 + q4 * 4;
                f32x4 a = acc[mt];
                lT[(b * 128 + i0 + 0) * 64 + m] = f2b(a[0]);
                lT[(b * 128 + i0 + 1) * 64 + m] = f2b(a[1]);
                lT[(b * 128 + i0 + 2) * 64 + m] = f2b(a[2]);
                lT[(b * 128 + i0 + 3) * 64 + m] = f2b(a[3]);
            }
        }
        return;
    }
    {
        int r = bid - 800;
        int b = r >> 6, i = r & 63;
        int j = t & 63, pg = t >> 6;
#pragma unroll
        for (int oc = 0; oc < 4; ++oc) {
            int p0 = pg * 32 + oc * 8;
            s16x8 v;
#pragma unroll
            for (int k = 0; k < 8; ++k)
                v[k] = (short)f2b(pre[((b * 128 + p0 + k) * 64 + i) * 64 + j]);
            *(s16x8*)(preT + ((b * 64 + i) * 64 + j) * 128 + p0) = v;
        }
    }
}

// ---------------- K2: fused attention + conv1, exp-once softmax. Block (b, e=i).
__global__ __launch_bounds__(256) void k_attnc(const float* __restrict__ Xs, const float* __restrict__ Yo,
                                               const u16* __restrict__ xfb, const u16* __restrict__ yfb,
                                               const float* __restrict__ xfT, const float* __restrict__ yfT,
                                               const int* __restrict__ path_mat, const float* __restrict__ p_bias,
                                               const float* __restrict__ ptab, const float* __restrict__ pconv,
                                               const u16* __restrict__ preT, const u16* __restrict__ wA1,
                                               const float* __restrict__ b1, u16* __restrict__ hT) {
    int b = blockIdx.x >> 6, e = blockIdx.x & 63;
    int t = threadIdx.x;
    int lane = t & 63, w = t >> 6;
    __shared__ __align__(16) char smem0[64 * 264 * 2];   // sAf f32[64][68] aliased with sMen u16[64][264]
    float* sAf = (float*)smem0;
    u16* sMen = (u16*)smem0;
    __shared__ u16 Abf[64][72];
    __shared__ u16 E2bf[64][72];
    __shared__ float sRed[256];   // [0:64) rmax, [64:128) rinv, [128:192) er2, [192:256) cinv
    __shared__ float sPdot[20];
    __shared__ float sXv[64], sYv[64];

    int tr = t >> 2, tq = t & 3, tn0 = tq * 16;

    if (t < 20) {
        float s = 0.f;
        for (int d = 0; d < 32; ++d) s += ptab[t * 32 + d] * pconv[d];
        sPdot[t] = lk(s);
    } else if (t >= 64 && t < 128) {
        sXv[t - 64] = Xs[b * 64 + t - 64];
    } else if (t >= 128 && t < 192) {
        sYv[t - 128] = Yo[b * 64 + t - 128];
    }
    __syncthreads();

    // P1: local scores + inline row max (4 threads/row, shfl reduce)
    {
        int base = (((b * 64 + e) * 64 + tr) * 64 + tn0);
        const int4* pm4 = (const int4*)(path_mat + base);
        const float4* pb4 = (const float4*)(p_bias + base);
        float yom = sYv[tr];
        float mx = -1e30f;
#pragma unroll
        for (int q2 = 0; q2 < 4; ++q2) {
            int4 pm = pm4[q2]; float4 pb = pb4[q2];
            int n = tn0 + q2 * 4;
            float4 v;
            v.x = lk(sXv[n + 0] + yom) + sPdot[pm.x] + pb.x;
            v.y = lk(sXv[n + 1] + yom) + sPdot[pm.y] + pb.y;
            v.z = lk(sXv[n + 2] + yom) + sPdot[pm.z] + pb.z;
            v.w = lk(sXv[n + 3] + yom) + sPdot[pm.w] + pb.w;
            *(float4*)&sAf[tr * 68 + n] = v;
            mx = fmaxf(mx, fmaxf(fmaxf(v.x, v.y), fmaxf(v.z, v.w)));
        }
        mx = fmaxf(mx, __shfl_xor(mx, 1));
        mx = fmaxf(mx, __shfl_xor(mx, 2));
        if (tq == 0) sRed[tr] = mx;
    }
    __syncthreads();

    // P2: wave0: global M + er2[m]=exp(rmax-M); all: E=exp(v-rmax) in place + rowsum
    if (t < 64) {
        float rm = sRed[t];
        float M = rm;
#pragma unroll
        for (int off = 1; off < 64; off <<= 1) M = fmaxf(M, __shfl_xor(M, off));
        sRed[128 + t] = __expf(rm - M);
    }
    {
        float rmax = sRed[tr];
        float4* rp = (float4*)&sAf[tr * 68 + tn0];
        float s = 0.f;
#pragma unroll
        for (int q2 = 0; q2 < 4; ++q2) {
            float4 v = rp[q2];
            float4 ev;
            ev.x = __expf(v.x - rmax); ev.y = __expf(v.y - rmax);
            ev.z = __expf(v.z - rmax); ev.w = __expf(v.w - rmax);
            s += ev.x + ev.y + ev.z + ev.w;
            rp[q2] = ev;
        }
        s += __shfl_xor(s, 1);
        s += __shfl_xor(s, 2);
        if (tq == 0) sRed[64 + tr] = 1.f / s;
    }
    __syncthreads();

    // P2c: col sums of E*er2  (col-softmax denominator, no exps)
    {
        float cs = 0.f;
#pragma unroll
        for (int k = 0; k < 16; ++k) {
            int mm = tn0 + k;
            cs += sAf[mm * 68 + tr] * sRed[128 + mm];
        }
        cs += __shfl_xor(cs, 1);
        cs += __shfl_xor(cs, 2);
        if (tq == 0) sRed[192 + tr] = 1.f / cs;
    }
    __syncthreads();

    // P3: pack Abf (row softmax) and E2bf (col softmax, transposed) — no exps
    {
        float rinv = sRed[64 + tr];
        const float4* rp = (const float4*)&sAf[tr * 68 + tn0];
#pragma unroll
        for (int g2 = 0; g2 < 2; ++g2) {
            float4 v0 = rp[g2 * 2], v1 = rp[g2 * 2 + 1];
            s16x8 pk;
            pk[0] = (short)f2b(v0.x * rinv); pk[1] = (short)f2b(v0.y * rinv);
            pk[2] = (short)f2b(v0.z * rinv); pk[3] = (short)f2b(v0.w * rinv);
            pk[4] = (short)f2b(v1.x * rinv); pk[5] = (short)f2b(v1.y * rinv);
            pk[6] = (short)f2b(v1.z * rinv); pk[7] = (short)f2b(v1.w * rinv);
            *(s16x8*)&Abf[tr][tn0 + g2 * 8] = pk;
        }
    }
    {
        float cinv = sRed[192 + tr];
#pragma unroll
        for (int g2 = 0; g2 < 2; ++g2) {
            s16x8 pk;
#pragma unroll
            for (int k = 0; k < 8; ++k) {
                int mm = tn0 + g2 * 8 + k;
                pk[k] = (short)f2b(sAf[mm * 68 + tr] * sRed[128 + mm] * cinv);
            }
            *(s16x8*)&E2bf[tr][tn0 + g2 * 8] = pk;
        }
    }
    __syncthreads();   // sAf dead; sMen may be written now

    int l15 = lane & 15, q4 = lane >> 4;
    // GEMM1: xret[c][m] -> sMen[m][c], c<128
    {
        f32x4 acc[2][4];
#pragma unroll
        for (int ci = 0; ci < 2; ++ci)
#pragma unroll
            for (int mt = 0; mt < 4; ++mt) acc[ci][mt] = (f32x4)(0.f);
#pragma unroll
        for (int kt = 0; kt < 2; ++kt) {
            s16x8 afr[2];
#pragma unroll
            for (int ci = 0; ci < 2; ++ci) {
                int c = (2 * w + ci) * 16 + l15;
                afr[ci] = *(const s16x8*)(yfb + (b * 128 + c) * 64 + kt * 32 + q4 * 8);
            }
            s16x8 bfr[4];
#pragma unroll
            for (int mt = 0; mt < 4; ++mt)
                bfr[mt] = *(const s16x8*)&Abf[mt * 16 + l15][kt * 32 + q4 * 8];
#pragma unroll
            for (int ci = 0; ci < 2; ++ci)
#pragma unroll
                for (int mt = 0; mt < 4; ++mt)
                    acc[ci][mt] = __builtin_amdgcn_mfma_f32_16x16x32_bf16(afr[ci], bfr[mt], acc[ci][mt], 0, 0, 0);
        }
#pragma unroll
        for (int ci = 0; ci < 2; ++ci) {
            int c0 = (2 * w + ci) * 16 + q4 * 4;
#pragma unroll
            for (int mt = 0; mt < 4; ++mt) {
                int m = mt * 16 + l15;
                float4 res = *(const float4*)(xfT + (b * 64 + m) * 128 + c0);
                f32x4 a = acc[ci][mt];
                u32 lo = (u32)f2b(lk(a[0] + res.x)) | ((u32)f2b(lk(a[1] + res.y)) << 16);
                u32 hi = (u32)f2b(lk(a[2] + res.z)) | ((u32)f2b(lk(a[3] + res.w)) << 16);
                *(uint2*)&sMen[m * 264 + c0] = make_uint2(lo, hi);
            }
        }
    }
    // GEMM2: yret[c][n] -> sMen[n][128+c]
    {
        f32x4 acc[2][4];
#pragma unroll
        for (int ci = 0; ci < 2; ++ci)
#pragma unroll
            for (int nt = 0; nt < 4; ++nt) acc[ci][nt] = (f32x4)(0.f);
#pragma unroll
        for (int kt = 0; kt < 2; ++kt) {
            s16x8 afr[2];
#pragma unroll
            for (int ci = 0; ci < 2; ++ci) {
                int c = (2 * w + ci) * 16 + l15;
                afr[ci] = *(const s16x8*)(xfb + (b * 128 + c) * 64 + kt * 32 + q4 * 8);
            }
            s16x8 bfr[4];
#pragma unroll
            for (int nt = 0; nt < 4; ++nt)
                bfr[nt] = *(const s16x8*)&E2bf[nt * 16 + l15][kt * 32 + q4 * 8];
#pragma unroll
            for (int ci = 0; ci < 2; ++ci)
#pragma unroll
                for (int nt = 0; nt < 4; ++nt)
                    acc[ci][nt] = __builtin_amdgcn_mfma_f32_16x16x32_bf16(afr[ci], bfr[nt], acc[ci][nt], 0, 0, 0);
        }
#pragma unroll
        for (int ci = 0; ci < 2; ++ci) {
            int c0 = (2 * w + ci) * 16 + q4 * 4;
#pragma unroll
            for (int nt = 0; nt < 4; ++nt) {
                int n = nt * 16 + l15;
                float4 res = *(const float4*)(yfT + (b * 64 + n) * 128 + c0);
                f32x4 a = acc[ci][nt];
                u32 lo = (u32)f2b(lk(a[0] + res.x)) | ((u32)f2b(lk(a[1] + res.y)) << 16);
                u32 hi = (u32)f2b(lk(a[2] + res.z)) | ((u32)f2b(lk(a[3] + res.w)) << 16);
                *(uint2*)&sMen[n * 264 + 128 + c0] = make_uint2(lo, hi);
            }
        }
    }
    __syncthreads();

    // conv1 for output row i=e: B from sMen (kc<8) / preT (kc>=8)
    {
        int wm = w & 1, wn = w >> 1;
        f32x4 acc[4][2];
#pragma unroll
        for (int mt = 0; mt < 4; ++mt)
#pragma unroll
            for (int nt = 0; nt < 2; ++nt) acc[mt][nt] = (f32x4)(0.f);
        const u16* prow = preT + (b * 64 + e) * 64 * 128;
        for (int kc = 0; kc < 12; ++kc) {
            s16x8 af[4];
#pragma unroll
            for (int mt = 0; mt < 4; ++mt)
                af[mt] = *(const s16x8*)(wA1 + (((kc * 8 + wm * 4 + mt) * 64 + lane) << 3));
            s16x8 bf[2];
#pragma unroll
            for (int nt = 0; nt < 2; ++nt) {
                int j = (wn * 2 + nt) * 16 + l15;
                bf[nt] = (kc < 8) ? *(const s16x8*)&sMen[j * 264 + kc * 32 + q4 * 8]
                                  : *(const s16x8*)(prow + j * 128 + (kc - 8) * 32 + q4 * 8);
            }
#pragma unroll
            for (int mt = 0; mt < 4; ++mt)
#pragma unroll
                for (int nt = 0; nt < 2; ++nt)
                    acc[mt][nt] = __builtin_amdgcn_mfma_f32_16x16x32_bf16(af[mt], bf[nt], acc[mt][nt], 0, 0, 0);
        }
#pragma unroll
        for (int mt = 0; mt < 4; ++mt) {
            int o0 = (wm * 4 + mt) * 16 + q4 * 4;
            float4 bb = *(const float4*)(b1 + o0);
#pragma unroll
            for (int nt = 0; nt < 2; ++nt) {
                int j = (wn * 2 + nt) * 16 + l15;
                f32x4 a = acc[mt][nt];
                u32 lo = (u32)f2b(lk(a[0] + bb.x)) | ((u32)f2b(lk(a[1] + bb.y)) << 16);
                u32 hi = (u32)f2b(lk(a[2] + bb.z)) | ((u32)f2b(lk(a[3] + bb.w)) << 16);
                *(uint2*)(hT + ((b * 64 + e) * 64 + j) * 128 + o0) = make_uint2(lo, hi);
            }
        }
    }
}

// ---------------- K3: conv2 (3x3 SAME) MFMA, LDS-staged halo (R6) + inline gbase (R7)
__global__ __launch_bounds__(256) void k_conv2(const u16* __restrict__ hT, const u16* __restrict__ wA2,
                                               const float* __restrict__ b2, const float* __restrict__ score_w,
                                               const float* __restrict__ Xs, const float* __restrict__ Yo,
                                               const float* __restrict__ etab, const float* __restrict__ econv,
                                               const int* __restrict__ edge_mat, const float* __restrict__ m_bias,
                                               float* __restrict__ m2r, float* __restrict__ g) {
    int b = blockIdx.x >> 6, i = blockIdx.x & 63;
    int t = threadIdx.x;
    int lane = t & 63, w = t >> 6, wm = w & 1, wn = w >> 1;
    int l15 = lane & 15, q4 = lane >> 4;
    __shared__ u16 sB2[3][66][136];
    __shared__ float sSc[2][64];
    __shared__ float sEd[16];

    if (t >= 240 && t < 250) {
        int et = t - 240;
        float s = 0.f;
        for (int d = 0; d < 32; ++d) s += etab[et * 32 + d] * econv[d];
        sEd[et] = lk(s);
    }
#pragma unroll
    for (int q = 0; q < 2; ++q) {
        int u = q * 256 + t;
        if (u < 384) {
            int r = u >> 7, rem = u & 127, hcol = rem >> 6, c2 = rem & 63;
            *(u32*)&sB2[r][hcol ? 65 : 0][c2 * 2] = 0u;
        }
    }
#pragma unroll
    for (int it = 0; it < 12; ++it) {
        int u = it * 256 + t;
        int cg = u & 15, j = (u >> 4) & 63, r = u >> 10;
        int ir = i - 1 + r;
        int4 v = make_int4(0, 0, 0, 0);
        if (ir >= 0 && ir < 64)
            v = *(const int4*)(hT + ((b * 64 + ir) * 64 + j) * 128 + cg * 8);
        *(int4*)&sB2[r][j + 1][cg * 8] = v;
    }
    __syncthreads();

    f32x4 acc[4][2];
#pragma unroll
    for (int mt = 0; mt < 4; ++mt)
#pragma unroll
        for (int nt = 0; nt < 2; ++nt) acc[mt][nt] = (f32x4)(0.f);

    for (int kc = 0; kc < 4; ++kc) {
#pragma unroll
        for (int tap = 0; tap < 9; ++tap) {
            int di = tap / 3, dj = tap % 3;
            s16x8 af[4];
#pragma unroll
            for (int mt = 0; mt < 4; ++mt)
                af[mt] = *(const s16x8*)(wA2 + ((((tap * 4 + kc) * 8 + wm * 4 + mt) * 64 + lane) << 3));
#pragma unroll
            for (int nt = 0; nt < 2; ++nt) {
                int jin = wn * 32 + nt * 16 + l15 + dj;
                s16x8 bf = *(const s16x8*)(&sB2[di][jin][kc * 32 + q4 * 8]);
#pragma unroll
                for (int mt = 0; mt < 4; ++mt)
                    acc[mt][nt] = __builtin_amdgcn_mfma_f32_16x16x32_bf16(af[mt], bf, acc[mt][nt], 0, 0, 0);
            }
        }
    }

    float part[2] = {0.f, 0.f};
#pragma unroll
    for (int mt = 0; mt < 4; ++mt) {
        int o0 = wm * 64 + mt * 16 + q4 * 4;
        float4 bb = *(const float4*)(b2 + o0);
        float4 sw = *(const float4*)(score_w + o0);
#pragma unroll
        for (int nt = 0; nt < 2; ++nt) {
            int j = wn * 32 + nt * 16 + l15;
            f32x4 a = acc[mt][nt];
            float v0 = lk(a[0] + bb.x), v1 = lk(a[1] + bb.y);
            float v2 = lk(a[2] + bb.z), v3 = lk(a[3] + bb.w);
            float* dst = m2r + ((b * 128 + o0) * 64 + i) * 64 + j;
            dst[0] = v0; dst[4096] = v1; dst[8192] = v2; dst[12288] = v3;
            part[nt] += sw.x * v0 + sw.y * v1 + sw.z * v2 + sw.w * v3;
        }
    }
#pragma unroll
    for (int nt = 0; nt < 2; ++nt) {
        float p = part[nt];
        p += __shfl_xor(p, 16);
        p += __shfl_xor(p, 32);
        if (q4 == 0) sSc[wm][wn * 32 + nt * 16 + l15] = p;
    }
    __syncthreads();
    if (t < 64) {
        float s = sSc[0][t] + sSc[1][t];
        int gi = (b * 64 + i) * 64 + t;
        float L = lk(Xs[b * 64 + t] + Yo[b * 64 + i]);
        g[gi] = L + sEd[edge_mat[gi]] + m_bias[gi] + lk(s);
    }
}

// ---------------- K4: final softmax+GEMM+residual, exp-once, block=(b, direction)
__global__ __launch_bounds__(256) void k_gout(const float* __restrict__ g,
                                              const u16* __restrict__ xlT, const u16* __restrict__ ylT,
                                              const float* __restrict__ x, const float* __restrict__ y,
                                              float* __restrict__ out) {
    int b = blockIdx.x >> 1, which = blockIdx.x & 1;
    int t = threadIdx.x;
    int lane = t & 63, w = t >> 6, l15 = lane & 15, q4 = lane >> 4;
    __shared__ float sG[64][68];
    __shared__ u16 Gbf[64][72];
    __shared__ float sRed[256];

    int tr = t >> 2, tq = t & 3, tn0 = tq * 16;

    // load row tr + inline row max
    {
        const float4* gp = (const float4*)(g + b * 4096 + tr * 64 + tn0);
        float mx = -1e30f;
#pragma unroll
        for (int q2 = 0; q2 < 4; ++q2) {
            float4 v = gp[q2];
            *(float4*)&sG[tr][tn0 + q2 * 4] = v;
            mx = fmaxf(mx, fmaxf(fmaxf(v.x, v.y), fmaxf(v.z, v.w)));
        }
        mx = fmaxf(mx, __shfl_xor(mx, 1));
        mx = fmaxf(mx, __shfl_xor(mx, 2));
        if (tq == 0) sRed[tr] = mx;
    }
    __syncthreads();
    if (t < 64) {
        float rm = sRed[t], M = rm;
#pragma unroll
        for (int off = 1; off < 64; off <<= 1) M = fmaxf(M, __shfl_xor(M, off));
        sRed[128 + t] = __expf(rm - M);
    }
    {
        float rmax = sRed[tr];
        float4* rp = (float4*)&sG[tr][tn0];
        float s = 0.f;
#pragma unroll
        for (int q2 = 0; q2 < 4; ++q2) {
            float4 v = rp[q2];
            float4 ev;
            ev.x = __expf(v.x - rmax); ev.y = __expf(v.y - rmax);
            ev.z = __expf(v.z - rmax); ev.w = __expf(v.w - rmax);
            s += ev.x + ev.y + ev.z + ev.w;
            rp[q2] = ev;
        }
        s += __shfl_xor(s, 1);
        s += __shfl_xor(s, 2);
        if (tq == 0) sRed[64 + tr] = 1.f / s;
    }
    __syncthreads();

    if (which == 0) {
        float rinv = sRed[64 + tr];
        const float4* rp = (const float4*)&sG[tr][tn0];
#pragma unroll
        for (int g2 = 0; g2 < 2; ++g2) {
            float4 v0 = rp[g2 * 2], v1 = rp[g2 * 2 + 1];
            s16x8 pk;
            pk[0] = (short)f2b(v0.x * rinv); pk[1] = (short)f2b(v0.y * rinv);
            pk[2] = (short)f2b(v0.z * rinv); pk[3] = (short)f2b(v0.w * rinv);
            pk[4] = (short)f2b(v1.x * rinv); pk[5] = (short)f2b(v1.y * rinv);
            pk[6] = (short)f2b(v1.z * rinv); pk[7] = (short)f2b(v1.w * rinv);
            *(s16x8*)&Gbf[tr][tn0 + g2 * 8] = pk;
        }
    } else {
        // col sums of E*er2
        float cs = 0.f;
#pragma unroll
        for (int k = 0; k < 16; ++k) {
            int mm = tn0 + k;
            cs += sG[mm][tr] * sRed[128 + mm];
        }
        cs += __shfl_xor(cs, 1);
        cs += __shfl_xor(cs, 2);
        if (tq == 0) sRed[192 + tr] = 1.f / cs;
    }
    __syncthreads();
    if (which == 1) {
        float cinv = sRed[192 + tr];
#pragma unroll
        for (int g2 = 0; g2 < 2; ++g2) {
            s16x8 pk;
#pragma unroll
            for (int k = 0; k < 8; ++k) {
                int mm = tn0 + g2 * 8 + k;
                pk[k] = (short)f2b(sG[mm][tr] * sRed[128 + mm] * cinv);
            }
            *(s16x8*)&Gbf[tr][tn0 + g2 * 8] = pk;
        }
    }
    __syncthreads();

    const u16* lT = which ? xlT : ylT;
    const float* res = which ? y : x;
    int off = which ? 65536 : 0;
    int mcol = w * 16 + l15;
    f32x4 acc[8];
#pragma unroll
    for (int mt = 0; mt < 8; ++mt) acc[mt] = (f32x4)(0.f);
#pragma unroll
    for (int kt = 0; kt < 2; ++kt) {
        s16x8 bfr = *(const s16x8*)&Gbf[mcol][kt * 32 + q4 * 8];
#pragma unroll
        for (int mt = 0; mt < 8; ++mt) {
            s16x8 af = *(const s16x8*)(lT + (b * 128 + mt * 16 + l15) * 64 + kt * 32 + q4 * 8);
            acc[mt] = __builtin_amdgcn_mfma_f32_16x16x32_bf16(af, bfr, acc[mt], 0, 0, 0);
        }
    }
#pragma unroll
    for (int mt = 0; mt < 8; ++mt) {
        int i0 = mt * 16 + q4 * 4;
        f32x4 a = acc[mt];
#pragma unroll
        for (int r = 0; r < 4; ++r) {
            int ad = (b * 128 + i0 + r) * 64 + mcol;
            out[off + ad] = a[r] + res[ad];
        }
    }
}

extern "C" void kernel_launch(void* const* d_in, const int* in_sizes, int n_in,
                              void* d_out, int out_size, void* d_ws, size_t ws_size,
                              hipStream_t stream) {
    const float* x = (const float*)d_in[0];
    const float* y = (const float*)d_in[1];
    const float* m_bias = (const float*)d_in[2];
    const int* edge_mat = (const int*)d_in[3];
    const float* p_bias = (const float*)d_in[4];
    const int* path_mat = (const int*)d_in[5];
    const float* pre = (const float*)d_in[6];
    const float* xc1 = (const float*)d_in[7];
    const float* yc1 = (const float*)d_in[8];
    const float* xc2w = (const float*)d_in[9];
    const float* xc2b = (const float*)d_in[10];
    const float* yc2w = (const float*)d_in[11];
    const float* yc2b = (const float*)d_in[12];
    const float* pconv = (const float*)d_in[13];
    const float* econv = (const float*)d_in[14];
    const float* w1 = (const float*)d_in[15];
    const float* b1 = (const float*)d_in[16];
    const float* w2 = (const float*)d_in[17];
    const float* b2 = (const float*)d_in[18];
    const float* score_w = (const float*)d_in[19];
    const float* xlw = (const float*)d_in[20];
    const float* ylw = (const float*)d_in[21];
    const float* etab = (const float*)d_in[22];
    const float* ptab = (const float*)d_in[23];

    float* Xs = (float*)d_ws;               // 512 f
    float* Yo = Xs + 512;                   // 512 f
    float* g = Yo + 512;                    // 32768 f
    float* xfT = g + 32768;                 // 65536 f
    float* yfT = xfT + 65536;               // 65536 f
    u16* wA1 = (u16*)(yfT + 65536);         // 49152 u16
    u16* wA2 = wA1 + 49152;                 // 147456 u16
    u16* xfb = wA2 + 147456;                // 65536 u16
    u16* yfb = xfb + 65536;
    u16* xlT = yfb + 65536;
    u16* ylT = xlT + 65536;
    u16* preT = ylT + 65536;                // 4194304 u16 (8 MiB)
    u16* hT = preT + 4194304;               // 4194304 u16 (8 MiB)

    float* out = (float*)d_out;
    float* out_m2r = out + 131072;

    hipLaunchKernelGGL(k_prep, dim3(1312), dim3(256), 0, stream, w1, w2, wA1, wA2,
                       x, y, xc1, yc1, xc2w, xc2b, yc2w, yc2b, xlw, ylw,
                       xfb, yfb, xfT, yfT, xlT, ylT, Xs, Yo, pre, preT);
    hipLaunchKernelGGL(k_attnc, dim3(512), dim3(256), 0, stream, Xs, Yo, xfb, yfb, xfT, yfT,
                       path_mat, p_bias, ptab, pconv, preT, wA1, b1, hT);
    hipLaunchKernelGGL(k_conv2, dim3(512), dim3(256), 0, stream, hT, wA2, b2, score_w,
                       Xs, Yo, etab, econv, edge_mat, m_bias, out_m2r, g);
    hipLaunchKernelGGL(k_gout, dim3(16), dim3(256), 0, stream, g, xlT, ylT, x, y, out);
}